// Round 7
// baseline (577.741 us; speedup 1.0000x reference)
//
#include <hip/hip_runtime.h>
#include <hip/hip_bf16.h>
#include <math.h>
#include <stdint.h>

#define L_SEQ 2048
#define BATCH 16
#define NROWS (BATCH * L_SEQ)   // 32768
#define DMODEL 256
#define DINNER 512
#define C_CH 32                  // chunks per sequence
#define T_CH 64                  // steps per chunk
#define LOG2E 1.4426950408889634f

typedef __attribute__((ext_vector_type(8))) __bf16 bf16x8;
typedef __attribute__((ext_vector_type(4))) float f32x4;
typedef __attribute__((ext_vector_type(8))) unsigned short u16x8;
typedef __attribute__((address_space(1))) const uint32_t gu32;
typedef __attribute__((address_space(3))) uint32_t lu32;

#if __has_builtin(__builtin_amdgcn_exp2f)
#define EXP2F __builtin_amdgcn_exp2f
#else
#define EXP2F exp2f
#endif

__device__ __forceinline__ float sigmoidf_(float x) { return 1.f / (1.f + __expf(-x)); }

__device__ __forceinline__ unsigned short f2bf(float f) {
    union { float f; uint32_t u; } v; v.f = f;
    uint32_t r = v.u + 0x7FFF + ((v.u >> 16) & 1);
    return (unsigned short)(r >> 16);
}
__device__ __forceinline__ float bf2f(unsigned short h) {
    union { uint32_t u; float f; } v; v.u = ((uint32_t)h) << 16;
    return v.f;
}

__device__ __forceinline__ void gld16(const void* g, void* l) {
    __builtin_amdgcn_global_load_lds((gu32*)g, (lu32*)l, 16, 0, 0);
}

template <int N> __device__ __forceinline__ void waitv() {
    if constexpr (N == 0)       asm volatile("s_waitcnt vmcnt(0)" ::: "memory");
    else if constexpr (N == 3)  asm volatile("s_waitcnt vmcnt(3)" ::: "memory");
    else if constexpr (N == 4)  asm volatile("s_waitcnt vmcnt(4)" ::: "memory");
    else if constexpr (N == 6)  asm volatile("s_waitcnt vmcnt(6)" ::: "memory");
    else if constexpr (N == 8)  asm volatile("s_waitcnt vmcnt(8)" ::: "memory");
    else if constexpr (N == 16) asm volatile("s_waitcnt vmcnt(16)" ::: "memory");
}

// ---------------- prep: W (KxN f32) -> Wt (NxK bf16) ----------------
__global__ __launch_bounds__(256) void wtrans(const float* __restrict__ W,
                                              unsigned short* __restrict__ Wt, int K, int N) {
    int idx = blockIdx.x * 256 + threadIdx.x;
    if (idx < K * N) {
        int n = idx / K, k = idx % K;
        Wt[idx] = f2bf(W[(size_t)k * N + n]);
    }
}
// W (K x Nreal) -> Wt (Npad x K), zero-padded rows
__global__ __launch_bounds__(256) void wtrans_pad(const float* __restrict__ W,
                                                  unsigned short* __restrict__ Wt,
                                                  int K, int Nreal, int Npad) {
    int idx = blockIdx.x * 256 + threadIdx.x;
    if (idx < Npad * K) {
        int n = idx / K, k = idx % K;
        Wt[idx] = (n < Nreal) ? f2bf(W[(size_t)k * Nreal + n]) : (unsigned short)0;
    }
}

// ---------------- bf16 MFMA GEMM, double-buffered LDS + COUNTED vmcnt ----------------
// C(M x Nout) = A(MxK) @ Bt(NxK)^T.  Tile TM x TN; BK in {32, 64}.
// R1-R6 model: wall = slots x ~1.2us, slots = (blocks/CU x NT / resident), AND
// resident >= 2-3 is required for the memory system to stream (R6: 1 block/CU
// halved delivered staging BW -> fat 128x256 tile REGRESSED despite halving
// traffic). Sweet spot: LDS <= ~48-64KB (3 resident), BK=64 where K allows.
// Both operands must be prefetched one full round ahead via LDS (R5).
// Tiles with row-bytes >= 128 use the XOR swizzle (col ^= (row&7)<<4) on both the
// pre-swizzled global source and the LDS frag read (involution; rule 21).
template <int TM, int TN, int BK, bool A_F32, bool HAS_BIAS, bool HAS_RES, bool OUT_BF16>
__global__ __launch_bounds__(256) void gemm_bf16(
    const void* __restrict__ Aptr, const unsigned short* __restrict__ Bt,
    const float* __restrict__ bias, const float* __restrict__ res,
    void* __restrict__ Cout, int M, int N, int K, int Nout)
{
    constexpr int MR = TM / 32;                 // 16-row m-frags per wave (wave owns TM/2 rows)
    constexpr int NR = TN / 32;                 // 16-col n-frags per wave (wave owns TN/2 cols)
    constexpr int EWA = A_F32 ? 4 : 2;
    constexpr int RBA = BK * EWA;               // A tile row bytes
    constexpr int RBB = BK * 2;                 // B tile row bytes
    constexpr int ABYTES = TM * RBA;
    constexpr int BBYTES = TN * RBB;
    constexpr int OPSA = ABYTES / 4096;         // gld16 instrs per thread (A)
    constexpr int OPSB = BBYTES / 4096;
    constexpr int VOPS = OPSA + OPSB;
    constexpr bool SWZA = (RBA >= 128);
    constexpr bool SWZB = (RBB >= 128);
    constexpr int KK = BK / 32;                 // MFMA k-substeps per round
    __shared__ __align__(16) char Alds[2][ABYTES];
    __shared__ __align__(16) char Blds[2][BBYTES];
    const int tid = threadIdx.x;
    const int w = tid >> 6, lane = tid & 63;

    // bijective XCD-chunked swizzle (nwg % 8 == 0 for all our shapes)
    const int nwg = gridDim.x;
    const int q = nwg >> 3;
    const int wg = (blockIdx.x & 7) * q + (blockIdx.x >> 3);
    const int nx = N / TN;
    const int bm = (wg / nx) * TM, bn = (wg % nx) * TN;

    const int wr = (w >> 1) * (TM / 2), wc = (w & 1) * (TN / 2);
    const int fr = lane & 15, fq = lane >> 4;
    const size_t KbB = (size_t)K * 2;
    const size_t KbA = (size_t)K * EWA;

    const char* Ab = (const char*)Aptr;
    const char* Bb = (const char*)Bt;
    const int lds0 = w * 1024;                  // wave-uniform dest offset, bytes

    f32x4 acc[MR][NR];
#pragma unroll
    for (int m = 0; m < MR; m++)
#pragma unroll
        for (int n = 0; n < NR; n++) acc[m][n] = (f32x4){0.f, 0.f, 0.f, 0.f};

    auto stageA = [&](int buf, int k0) {
        char* lA = Alds[buf];
#pragma unroll
        for (int i = 0; i < OPSA; i++) {
            const int o = i * 4096 + tid * 16;
            const int row = o / RBA;
            int col = o % RBA;
            if constexpr (SWZA) col ^= (row & 7) << 4;
            gld16(Ab + (size_t)(bm + row) * KbA + (size_t)k0 * EWA + col,
                  lA + i * 4096 + lds0);
        }
    };
    auto stageB = [&](int buf, int k0) {
        char* lB = Blds[buf];
#pragma unroll
        for (int i = 0; i < OPSB; i++) {
            const int o = i * 4096 + tid * 16;
            const int row = o / RBB;
            int col = o % RBB;
            if constexpr (SWZB) col ^= (row & 7) << 4;
            gld16(Bb + (size_t)(bn + row) * KbB + (size_t)k0 * 2 + col,
                  lB + i * 4096 + lds0);
        }
    };
    auto compute = [&](int buf) {
        const char* lA = Alds[buf];
        const char* lB = Blds[buf];
#pragma unroll
        for (int kk = 0; kk < KK; kk++) {        // kk-outer keeps frag regs small
            bf16x8 af[MR], bg[NR];
#pragma unroll
            for (int m = 0; m < MR; m++) {
                const int row = wr + m * 16 + fr;
                const int sw = SWZA ? ((row & 7) << 4) : 0;
                if constexpr (A_F32) {
                    const int b0 = row * RBA + kk * 128 + fq * 32;
                    float4 x0 = *(const float4*)(lA + (b0 ^ sw));
                    float4 x1 = *(const float4*)(lA + ((b0 + 16) ^ sw));
                    bf16x8 a;
                    a[0]=(__bf16)x0.x; a[1]=(__bf16)x0.y; a[2]=(__bf16)x0.z; a[3]=(__bf16)x0.w;
                    a[4]=(__bf16)x1.x; a[5]=(__bf16)x1.y; a[6]=(__bf16)x1.z; a[7]=(__bf16)x1.w;
                    af[m] = a;
                } else {
                    const int c = kk * 64 + fq * 16;
                    af[m] = *(const bf16x8*)(lA + row * RBA + (c ^ sw));
                }
            }
#pragma unroll
            for (int n = 0; n < NR; n++) {
                const int row = wc + n * 16 + fr;
                const int sw = SWZB ? ((row & 7) << 4) : 0;
                const int c = kk * 64 + fq * 16;
                bg[n] = *(const bf16x8*)(lB + row * RBB + (c ^ sw));
            }
#pragma unroll
            for (int m = 0; m < MR; m++)
#pragma unroll
                for (int n = 0; n < NR; n++)
                    acc[m][n] = __builtin_amdgcn_mfma_f32_16x16x32_bf16(af[m], bg[n], acc[m][n], 0, 0, 0);
        }
    };

    const int NT = K / BK;

    // ---- prologue: stage tile 0 into buf 0, full drain once ----
    stageA(0, 0); stageB(0, 0);
    asm volatile("s_waitcnt vmcnt(0) lgkmcnt(0)" ::: "memory");
    __builtin_amdgcn_s_barrier();
    __builtin_amdgcn_sched_barrier(0);

    for (int kt = 0; kt < NT; ++kt) {
        const int cur = kt & 1;
        const bool has_next = (kt + 1 < NT);
        if (has_next) {
            const int k0 = (kt + 1) * BK;
            stageA(cur ^ 1, k0); stageB(cur ^ 1, k0);
            waitv<VOPS>();          // current tile only; next stays in flight
        } else {
            waitv<0>();
        }
        __builtin_amdgcn_s_barrier();
        __builtin_amdgcn_sched_barrier(0);

        compute(cur);

        asm volatile("s_waitcnt lgkmcnt(0)" ::: "memory");
        __builtin_amdgcn_s_barrier();
        __builtin_amdgcn_sched_barrier(0);
    }

#pragma unroll
    for (int m = 0; m < MR; m++) {
#pragma unroll
        for (int n = 0; n < NR; n++) {
            int col = bn + wc + n * 16 + fr;
            if (col < Nout) {
#pragma unroll
                for (int r = 0; r < 4; r++) {
                    int row = bm + wr + m * 16 + fq * 4 + r;
                    float v = acc[m][n][r];
                    if (HAS_BIAS) v += bias[col];
                    if (HAS_RES)  v += res[(size_t)row * Nout + col];
                    if (OUT_BF16) ((unsigned short*)Cout)[(size_t)row * Nout + col] = f2bf(v);
                    else          ((float*)Cout)[(size_t)row * Nout + col] = v;
                }
            }
        }
    }
}

// ---------------- LayerNorm over 256, f32 -> bf16 ----------------
__global__ __launch_bounds__(256) void ln256(
    const float* __restrict__ x, const float* __restrict__ g,
    const float* __restrict__ b, unsigned short* __restrict__ out)
{
    int lane = threadIdx.x & 63, wid = threadIdx.x >> 6;
    size_t r = (size_t)blockIdx.x * 4 + wid;
    const float4 v = *(const float4*)&x[r * 256 + lane * 4];
    float s = v.x + v.y + v.z + v.w;
    float sq = v.x * v.x + v.y * v.y + v.z * v.z + v.w * v.w;
#pragma unroll
    for (int off = 32; off; off >>= 1) { s += __shfl_xor(s, off); sq += __shfl_xor(sq, off); }
    float mean = s * (1.f / 256.f);
    float var = sq * (1.f / 256.f) - mean * mean;
    float rs = rsqrtf(var + 1e-5f);
    float4 gv = *(const float4*)&g[lane * 4];
    float4 bv = *(const float4*)&b[lane * 4];
    ushort4 o;
    o.x = f2bf((v.x - mean) * rs * gv.x + bv.x);
    o.y = f2bf((v.y - mean) * rs * gv.y + bv.y);
    o.z = f2bf((v.z - mean) * rs * gv.z + bv.z);
    o.w = f2bf((v.w - mean) * rs * gv.w + bv.w);
    *(ushort4*)&out[r * 256 + lane * 4] = o;
}

// ---------------- LayerNorm over 64 (final) f32 -> f32 ----------------
__global__ __launch_bounds__(256) void ln64(
    const float* __restrict__ t, const float* __restrict__ g,
    const float* __restrict__ b, float* __restrict__ out)
{
    int lane = threadIdx.x & 63, wid = threadIdx.x >> 6;
    size_t r = (size_t)blockIdx.x * 4 + wid;
    float v = t[r * 64 + lane];
    float s = v, sq = v * v;
#pragma unroll
    for (int off = 32; off; off >>= 1) { s += __shfl_xor(s, off); sq += __shfl_xor(sq, off); }
    float mean = s * (1.f / 64.f);
    float var = sq * (1.f / 64.f) - mean * mean;
    out[r * 64 + lane] = (v - mean) * rsqrtf(var + 1e-5f) * g[lane] + b[lane];
}

// ---------------- Depthwise causal conv (K=4) + bias + silu, 8 d per thread ----------------
__global__ __launch_bounds__(256) void conv_silu8(
    const unsigned short* __restrict__ xz, const float* __restrict__ w,
    const float* __restrict__ cb, unsigned short* __restrict__ xc)
{
    int idx = blockIdx.x * 256 + threadIdx.x;     // NROWS*64 threads
    int d8 = (idx & 63) << 3;                     // lane -> d-group (coalesced)
    int l  = (idx >> 6) & 2047;
    int b  = idx >> 17;
    const unsigned short* base = xz + ((size_t)b * L_SEQ + l) * 1024 + d8;
    u16x8 t0 = {0,0,0,0,0,0,0,0}, t1 = t0, t2 = t0;
    u16x8 t3 = *(const u16x8*)base;
    if (l >= 1) t2 = *(const u16x8*)(base - 1024);
    if (l >= 2) t1 = *(const u16x8*)(base - 2048);
    if (l >= 3) t0 = *(const u16x8*)(base - 3072);
    u16x8 o;
#pragma unroll
    for (int j = 0; j < 8; j++) {
        float4 wv = *(const float4*)&w[(d8 + j) * 4];
        float acc = cb[d8 + j];
        acc = fmaf(bf2f(t0[j]), wv.x, acc);
        acc = fmaf(bf2f(t1[j]), wv.y, acc);
        acc = fmaf(bf2f(t2[j]), wv.z, acc);
        acc = fmaf(bf2f(t3[j]), wv.w, acc);
        o[j] = f2bf(acc * sigmoidf_(acc));
    }
    *(u16x8*)&xc[((size_t)b * L_SEQ + l) * 512 + d8] = o;
}

// ---------------- Chunked selective scan (dt fused in-register; P stored as
// scalar Tsum per (b,c,d) -- P[n]=exp2(Tsum*a2[n]) is recomputed in pass2) ----------------
__global__ __launch_bounds__(256) void scan_pass1(
    const unsigned short* __restrict__ xc, const float* __restrict__ xdbl,
    const float* __restrict__ Wdt, const float* __restrict__ bdt,
    const float* __restrict__ Alog,
    float* __restrict__ Tbuf, float* __restrict__ Sbuf)
{
    __shared__ float xs[T_CH][32];   // [t][0:16]=dt-proj inputs, [16:32]=B
    int idx = blockIdx.x * 256 + threadIdx.x;
    int d = idx & 511;
    int c = (idx >> 9) & (C_CH - 1);
    int b = idx >> 14;
    size_t r0 = (size_t)b * L_SEQ + (size_t)c * T_CH;
#pragma unroll
    for (int ii = 0; ii < 2; ii++) {
        int i = threadIdx.x + ii * 256, row = i >> 3, qq = i & 7;
        *(float4*)&xs[row][qq * 4] = *(const float4*)&xdbl[(r0 + row) * 48 + qq * 4];
    }
    __syncthreads();

    float wdt[16];
#pragma unroll
    for (int j = 0; j < 16; j++) wdt[j] = Wdt[j * 512 + d];
    const float bd = bdt[d];

    float a[16], a2[16], S[16];
#pragma unroll
    for (int n = 0; n < 16; n++) a[n] = -__expf(Alog[d * 16 + n]);
#pragma unroll
    for (int n = 0; n < 16; n++) a2[n] = a[n] * LOG2E;
#pragma unroll
    for (int n = 0; n < 16; n++) S[n] = 0.f;
    bool pow_ok = true;
#pragma unroll
    for (int n = 1; n < 16; n++)
        pow_ok = pow_ok && (fabsf(a[n] - (n + 1) * a[0]) <= 1e-3f * (n + 1) * fabsf(a[0]));
    const float a0l2 = a[0] * LOG2E;
    float Tsum = 0.f;

    if (pow_ok) {
        for (int t = 0; t < T_CH; t++) {
            float dtr = bd;
#pragma unroll
            for (int j = 0; j < 16; j++) dtr = fmaf(xs[t][j], wdt[j], dtr);
            float dtv = (dtr > 20.f) ? dtr : __logf(1.f + __expf(dtr));
            float u = bf2f(xc[(r0 + t) * 512 + d]);
            float dtu = dtv * u;
            Tsum += dtv;
            float e1 = EXP2F(dtv * a0l2), e2 = e1 * e1;
            S[0] = fmaf(e1, S[0], dtu * xs[t][16]);
            S[1] = fmaf(e2, S[1], dtu * xs[t][17]);
            float pm2 = e1, pm1 = e2;
#pragma unroll
            for (int n = 2; n < 16; n++) {
                float cur = pm2 * e2;
                S[n] = fmaf(cur, S[n], dtu * xs[t][16 + n]);
                pm2 = pm1; pm1 = cur;
            }
        }
    } else {
        for (int t = 0; t < T_CH; t++) {
            float dtr = bd;
#pragma unroll
            for (int j = 0; j < 16; j++) dtr = fmaf(xs[t][j], wdt[j], dtr);
            float dtv = (dtr > 20.f) ? dtr : __logf(1.f + __expf(dtr));
            float u = bf2f(xc[(r0 + t) * 512 + d]);
            float dtu = dtv * u;
            Tsum += dtv;
#pragma unroll
            for (int n = 0; n < 16; n++) {
                float dA = EXP2F(dtv * a2[n]);
                S[n] = fmaf(dA, S[n], dtu * xs[t][16 + n]);
            }
        }
    }
    Tbuf[idx] = Tsum;
    size_t o = (size_t)idx * 16;
#pragma unroll
    for (int qq = 0; qq < 4; qq++)
        *(float4*)&Sbuf[o + qq * 4] = make_float4(S[qq*4], S[qq*4+1], S[qq*4+2], S[qq*4+3]);
}

__global__ __launch_bounds__(256) void scan_pass2(
    const float* __restrict__ Tbuf, const float* __restrict__ Alog,
    float* __restrict__ Sbuf)
{
    int g = blockIdx.x * 256 + threadIdx.x;
    int nd = g & 8191;
    int b = g >> 13;
    int d = nd >> 4, n = nd & 15;
    const float a2 = -__expf(Alog[d * 16 + n]) * LOG2E;
    float H = 0.f;
    for (int c = 0; c < C_CH; c++) {
        size_t base = (size_t)(b * C_CH + c);
        float T = Tbuf[base * 512 + d];
        float P = EXP2F(T * a2);
        size_t idx = base * 8192 + nd;
        float S = Sbuf[idx];
        float Hn = fmaf(P, H, S);
        Sbuf[idx] = H;
        H = Hn;
    }
}

__global__ __launch_bounds__(256) void scan_pass3(
    const unsigned short* __restrict__ xcin, const unsigned short* __restrict__ xz,
    const float* __restrict__ xdbl, const float* __restrict__ Wdt,
    const float* __restrict__ bdt, const float* __restrict__ Alog,
    const float* __restrict__ Dsk, const float* __restrict__ Sbuf,
    unsigned short* __restrict__ y)
{
    __shared__ float xs[T_CH][48];   // [t][0:16]=dt-in, [16:32]=B, [32:48]=C
    int idx = blockIdx.x * 256 + threadIdx.x;
    int d = idx & 511;
    int c = (idx >> 9) & (C_CH - 1);
    int b = idx >> 14;
    size_t r0 = (size_t)b * L_SEQ + (size_t)c * T_CH;
#pragma unroll
    for (int ii = 0; ii < 3; ii++) {
        int i = threadIdx.x + ii * 256, row = i / 12, qq = i % 12;
        *(float4*)&xs[row][qq * 4] = *(const float4*)&xdbl[(r0 + row) * 48 + qq * 4];
    }
    __syncthreads();

    float wdt[16];
#pragma unroll
    for (int j = 0; j < 16; j++) wdt[j] = Wdt[j * 512 + d];
    const float bd = bdt[d];

    float a[16], a2[16], h[16];
#pragma unroll
    for (int n = 0; n < 16; n++) a[n] = -__expf(Alog[d * 16 + n]);
#pragma unroll
    for (int n = 0; n < 16; n++) a2[n] = a[n] * LOG2E;
    {
        size_t o = (size_t)idx * 16;
#pragma unroll
        for (int qq = 0; qq < 4; qq++) {
            float4 v = *(const float4*)&Sbuf[o + qq * 4];
            h[qq*4] = v.x; h[qq*4+1] = v.y; h[qq*4+2] = v.z; h[qq*4+3] = v.w;
        }
    }
    bool pow_ok = true;
#pragma unroll
    for (int n = 1; n < 16; n++)
        pow_ok = pow_ok && (fabsf(a[n] - (n + 1) * a[0]) <= 1e-3f * (n + 1) * fabsf(a[0]));
    const float a0l2 = a[0] * LOG2E;
    const float Dv = Dsk[d];

    if (pow_ok) {
        for (int t = 0; t < T_CH; t++) {
            size_t ridx = (r0 + t) * 512 + d;
            float dtr = bd;
#pragma unroll
            for (int j = 0; j < 16; j++) dtr = fmaf(xs[t][j], wdt[j], dtr);
            float dtv = (dtr > 20.f) ? dtr : __logf(1.f + __expf(dtr));
            float u = bf2f(xcin[ridx]);
            float dtu = dtv * u;
            float e1 = EXP2F(dtv * a0l2), e2 = e1 * e1;
            float yv = 0.f;
            h[0] = fmaf(e1, h[0], dtu * xs[t][16]);  yv = fmaf(h[0], xs[t][32], yv);
            h[1] = fmaf(e2, h[1], dtu * xs[t][17]);  yv = fmaf(h[1], xs[t][33], yv);
            float pm2 = e1, pm1 = e2;
#pragma unroll
            for (int n = 2; n < 16; n++) {
                float cur = pm2 * e2;
                h[n] = fmaf(cur, h[n], dtu * xs[t][16 + n]);
                yv = fmaf(h[n], xs[t][32 + n], yv);
                pm2 = pm1; pm1 = cur;
            }
            yv = fmaf(u, Dv, yv);
            float z = bf2f(xz[(r0 + t) * 1024 + 512 + d]);
            y[ridx] = f2bf(yv * z * sigmoidf_(z));
        }
    } else {
        for (int t = 0; t < T_CH; t++) {
            size_t ridx = (r0 + t) * 512 + d;
            float dtr = bd;
#pragma unroll
            for (int j = 0; j < 16; j++) dtr = fmaf(xs[t][j], wdt[j], dtr);
            float dtv = (dtr > 20.f) ? dtr : __logf(1.f + __expf(dtr));
            float u = bf2f(xcin[ridx]);
            float dtu = dtv * u;
            float yv = 0.f;
#pragma unroll
            for (int n = 0; n < 16; n++) {
                float dA = EXP2F(dtv * a2[n]);
                h[n] = fmaf(dA, h[n], dtu * xs[t][16 + n]);
                yv = fmaf(h[n], xs[t][32 + n], yv);
            }
            yv = fmaf(u, Dv, yv);
            float z = bf2f(xz[(r0 + t) * 1024 + 512 + d]);
            y[ridx] = f2bf(yv * z * sigmoidf_(z));
        }
    }
}

extern "C" void kernel_launch(void* const* d_in, const int* in_sizes, int n_in,
                              void* d_out, int out_size, void* d_ws, size_t ws_size,
                              hipStream_t stream)
{
    const float* z_t     = (const float*)d_in[0];
    const float* W_in    = (const float*)d_in[1];
    const float* b_in    = (const float*)d_in[2];
    const float* ln_g    = (const float*)d_in[3];
    const float* ln_b    = (const float*)d_in[4];
    const float* W_inpr  = (const float*)d_in[5];
    const float* conv_w  = (const float*)d_in[6];
    const float* conv_b  = (const float*)d_in[7];
    const float* W_xproj = (const float*)d_in[8];
    const float* W_dt    = (const float*)d_in[9];
    const float* b_dt    = (const float*)d_in[10];
    const float* A_log   = (const float*)d_in[11];
    const float* D_skip  = (const float*)d_in[12];
    const float* W_out   = (const float*)d_in[13];
    const float* W_outp  = (const float*)d_in[14];
    const float* b_outp  = (const float*)d_in[15];
    const float* lno_g   = (const float*)d_in[16];
    const float* lno_b   = (const float*)d_in[17];
    float* out           = (float*)d_out;

    // Workspace (~119 MB + weights)
    char* p = (char*)d_ws;
    float*          x    = (float*)p;          p += (size_t)NROWS * DMODEL * 4;      // 32 MB
    unsigned short* xn   = (unsigned short*)p; p += (size_t)NROWS * DMODEL * 2;      // 16 MB
    unsigned short* xc   = (unsigned short*)p; p += (size_t)NROWS * DINNER * 2;      // 32 MB
    unsigned short* xz   = (unsigned short*)p; p += (size_t)NROWS * 1024 * 2;        // 64 MB
    float*          xdbl = (float*)p;          p += (size_t)NROWS * 48 * 4;          // 6.3 MB
    float*          Pregion = (float*)p;       p += (size_t)BATCH * C_CH * DINNER * 16 * 4; // 16.8
    float*          Sbuf = (float*)p;          p += (size_t)BATCH * C_CH * DINNER * 16 * 4; // 16.8
    unsigned short* WinT  = (unsigned short*)p; p += (size_t)256 * 1088 * 2;
    unsigned short* WipT  = (unsigned short*)p; p += (size_t)2 * 1024 * 256 * 2;
    unsigned short* WoutT = (unsigned short*)p; p += (size_t)2 * 256 * 512 * 2;
    unsigned short* WxpT  = (unsigned short*)p; p += (size_t)2 * 128 * 512 * 2;
    unsigned short* WopT  = (unsigned short*)p; p += (size_t)128 * 256 * 2;
    // aliases (timeline-disjoint):
    float* Tbuf = Pregion;   // 1 MB: pass1 -> pass2, per layer
    float* otmp = Pregion;   // 8.4 MB: outp GEMM -> ln64 (after all scans)

    // prep: transpose weights to bf16 NxK
    wtrans<<<(256 * 1088 + 255) / 256, 256, 0, stream>>>(W_in, WinT, 1088, 256);
    for (int l = 0; l < 2; l++) {
        wtrans<<<(1024 * 256 + 255) / 256, 256, 0, stream>>>(
            W_inpr + (size_t)l * 256 * 1024, WipT + (size_t)l * 1024 * 256, 256, 1024);
        wtrans<<<(256 * 512 + 255) / 256, 256, 0, stream>>>(
            W_out + (size_t)l * 512 * 256, WoutT + (size_t)l * 256 * 512, 512, 256);
        wtrans_pad<<<(128 * 512 + 255) / 256, 256, 0, stream>>>(
            W_xproj + (size_t)l * 512 * 48, WxpT + (size_t)l * 128 * 512, 512, 48, 128);
    }
    wtrans_pad<<<(128 * 256 + 255) / 256, 256, 0, stream>>>(W_outp, WopT, 256, 64, 128);

    // x = z_t @ W_in + b_in   (R4 proven config: TM=64/TN=128/BK=64, 64KB LDS,
    // 2-3 resident blocks/CU -> measured 80us)
    gemm_bf16<64, 128, 64, true, true, false, false><<<(NROWS / 64) * (256 / 128), 256, 0, stream>>>(
        z_t, WinT, b_in, nullptr, x, NROWS, 256, 1088, 256);

    for (int layer = 0; layer < 2; ++layer) {
        ln256<<<NROWS / 4, 256, 0, stream>>>(x, ln_g + layer * 256, ln_b + layer * 256, xn);
        // inproj: TN=256 halves A duplication (8->4 N-tiles); 48KB LDS keeps 3
        // blocks/CU resident (the R6 lesson: residency >= 3 is the BW regime)
        gemm_bf16<128, 256, 32, false, false, false, true><<<(NROWS / 128) * (1024 / 256), 256, 0, stream>>>(
            xn, WipT + (size_t)layer * 1024 * 256, nullptr, nullptr, xz, NROWS, 1024, 256, 1024);
        conv_silu8<<<NROWS * 64 / 256, 256, 0, stream>>>(
            xz, conv_w + layer * 512 * 4, conv_b + layer * 512, xc);
        gemm_bf16<64, 128, 64, false, false, false, false><<<(NROWS / 64) * (128 / 128), 256, 0, stream>>>(
            xc, WxpT + (size_t)layer * 128 * 512, nullptr, nullptr, xdbl, NROWS, 128, 512, 48);

        const float* Al_l  = A_log + layer * 512 * 16;
        const float* Wdt_l = W_dt + layer * 16 * 512;
        const float* bdt_l = b_dt + layer * 512;
        scan_pass1<<<BATCH * C_CH * DINNER / 256, 256, 0, stream>>>(
            xc, xdbl, Wdt_l, bdt_l, Al_l, Tbuf, Sbuf);
        scan_pass2<<<BATCH * DINNER * 16 / 256, 256, 0, stream>>>(Tbuf, Al_l, Sbuf);
        scan_pass3<<<BATCH * C_CH * DINNER / 256, 256, 0, stream>>>(
            xc, xz, xdbl, Wdt_l, bdt_l, Al_l, D_skip + layer * 512, Sbuf, xc);

        if (layer == 0) {
            gemm_bf16<64, 128, 64, false, false, true, false><<<(NROWS / 64) * (256 / 128), 256, 0, stream>>>(
                xc, WoutT, nullptr, x, x, NROWS, 256, 512, 256);
        } else {
            // final residual add, emitted as bf16 directly (feeds out-proj GEMM)
            gemm_bf16<64, 128, 64, false, false, true, true><<<(NROWS / 64) * (256 / 128), 256, 0, stream>>>(
                xc, WoutT + (size_t)256 * 512, nullptr, x, xn, NROWS, 256, 512, 256);
        }
    }

    // out-proj via MFMA (N=64 padded to 128), then LN(64)
    gemm_bf16<64, 128, 32, false, true, false, false><<<(NROWS / 64) * (128 / 128), 256, 0, stream>>>(
        xn, WopT, b_outp, nullptr, otmp, NROWS, 128, 256, 64);
    ln64<<<NROWS / 4, 256, 0, stream>>>(otmp, lno_g, lno_b, out);
}

// Round 8
// 530.635 us; speedup vs baseline: 1.0888x; 1.0888x over previous
//
#include <hip/hip_runtime.h>
#include <hip/hip_bf16.h>
#include <math.h>
#include <stdint.h>

#define L_SEQ 2048
#define BATCH 16
#define NROWS (BATCH * L_SEQ)   // 32768
#define DMODEL 256
#define DINNER 512
#define C_CH 32                  // chunks per sequence
#define T_CH 64                  // steps per chunk
#define LOG2E 1.4426950408889634f

typedef __attribute__((ext_vector_type(8))) __bf16 bf16x8;
typedef __attribute__((ext_vector_type(4))) float f32x4;
typedef __attribute__((ext_vector_type(8))) unsigned short u16x8;
typedef __attribute__((address_space(1))) const uint32_t gu32;
typedef __attribute__((address_space(3))) uint32_t lu32;

#if __has_builtin(__builtin_amdgcn_exp2f)
#define EXP2F __builtin_amdgcn_exp2f
#else
#define EXP2F exp2f
#endif

__device__ __forceinline__ float sigmoidf_(float x) { return 1.f / (1.f + __expf(-x)); }

__device__ __forceinline__ unsigned short f2bf(float f) {
    union { float f; uint32_t u; } v; v.f = f;
    uint32_t r = v.u + 0x7FFF + ((v.u >> 16) & 1);
    return (unsigned short)(r >> 16);
}
__device__ __forceinline__ float bf2f(unsigned short h) {
    union { uint32_t u; float f; } v; v.u = ((uint32_t)h) << 16;
    return v.f;
}

__device__ __forceinline__ void gld16(const void* g, void* l) {
    __builtin_amdgcn_global_load_lds((gu32*)g, (lu32*)l, 16, 0, 0);
}

template <int N> __device__ __forceinline__ void waitv() {
    if constexpr (N == 0)       asm volatile("s_waitcnt vmcnt(0)" ::: "memory");
    else if constexpr (N == 3)  asm volatile("s_waitcnt vmcnt(3)" ::: "memory");
    else if constexpr (N == 4)  asm volatile("s_waitcnt vmcnt(4)" ::: "memory");
    else if constexpr (N == 6)  asm volatile("s_waitcnt vmcnt(6)" ::: "memory");
    else if constexpr (N == 8)  asm volatile("s_waitcnt vmcnt(8)" ::: "memory");
    else if constexpr (N == 16) asm volatile("s_waitcnt vmcnt(16)" ::: "memory");
}

// ---------------- prep: ALL weight transposes in one launch (8 -> 1 dispatch) ----
// seg layout (blocks): [0,1088) W_in | [1088,3136) W_inpr l0/l1 | [3136,4160)
// W_out l0/l1 | [4160,4672) W_xproj l0/l1 (pad 48->128) | [4672,4800) W_outp (pad 64->128)
__global__ __launch_bounds__(256) void wtrans_all(
    const float* __restrict__ W_in, const float* __restrict__ W_inpr,
    const float* __restrict__ W_out, const float* __restrict__ W_xproj,
    const float* __restrict__ W_outp,
    unsigned short* __restrict__ WinT, unsigned short* __restrict__ WipT,
    unsigned short* __restrict__ WoutT, unsigned short* __restrict__ WxpT,
    unsigned short* __restrict__ WopT)
{
    const int bid = blockIdx.x, tid = threadIdx.x;
    if (bid < 1088) {                              // W_in: K=1088, N=256
        int idx = bid * 256 + tid;
        int n = idx / 1088, k = idx % 1088;
        WinT[idx] = f2bf(W_in[(size_t)k * 256 + n]);
    } else if (bid < 3136) {                       // W_inpr: K=256, N=1024 (x2)
        int l = (bid - 1088) >> 10;
        int idx = ((bid - 1088) & 1023) * 256 + tid;
        int n = idx >> 8, k = idx & 255;
        WipT[(size_t)l * 262144 + idx] = f2bf(W_inpr[(size_t)l * 262144 + (size_t)k * 1024 + n]);
    } else if (bid < 4160) {                       // W_out: K=512, N=256 (x2)
        int l = (bid - 3136) >> 9;
        int idx = ((bid - 3136) & 511) * 256 + tid;
        int n = idx >> 9, k = idx & 511;
        WoutT[(size_t)l * 131072 + idx] = f2bf(W_out[(size_t)l * 131072 + (size_t)k * 256 + n]);
    } else if (bid < 4672) {                       // W_xproj: K=512, Nreal=48, Npad=128 (x2)
        int l = (bid - 4160) >> 8;
        int idx = ((bid - 4160) & 255) * 256 + tid;
        int n = idx >> 9, k = idx & 511;
        WxpT[(size_t)l * 65536 + idx] =
            (n < 48) ? f2bf(W_xproj[(size_t)l * (512 * 48) + (size_t)k * 48 + n]) : (unsigned short)0;
    } else {                                       // W_outp: K=256, Nreal=64, Npad=128
        int idx = (bid - 4672) * 256 + tid;
        int n = idx >> 8, k = idx & 255;
        WopT[idx] = (n < 64) ? f2bf(W_outp[(size_t)k * 64 + n]) : (unsigned short)0;
    }
}

// ---------------- bf16 MFMA GEMM, double-buffered LDS + COUNTED vmcnt ----------------
// C(M x Nout) = A(MxK) @ Bt(NxK)^T.  Tile TM x TN; BK in {32, 64}.
// R1-R7 model: wall = slots x ~2.2us, slots = blocks/CU x NT / resident;
// resident = min(LDS-cap, VGPR-cap, grid-cap) and must be >= 2-3 for the memory
// system to stream (R6). TN growth costs acc VGPRs quadratically (R7: 128x256
// inproj VGPR-capped residency at 2 -> regressed). R4 configs are the joint
// optimum: 64/128/BK64 for K-heavy, 128/128/BK32 for inproj.
// Both operands prefetched one full round ahead via LDS (R5). Row-bytes >= 128
// -> XOR swizzle (col ^= (row&7)<<4) on pre-swizzled source + frag read (rule 21).
// LN64OUT: fuse final LayerNorm(64) into the epilogue (Nout=64, NR=4: wc=0
// waves hold each row's full 64 cols; shfl_xor masks 1/2/4/8 stay in fr-group).
template <int TM, int TN, int BK, bool A_F32, bool HAS_BIAS, bool HAS_RES, bool OUT_BF16, bool LN64OUT>
__global__ __launch_bounds__(256) void gemm_bf16(
    const void* __restrict__ Aptr, const unsigned short* __restrict__ Bt,
    const float* __restrict__ bias, const float* __restrict__ res,
    void* __restrict__ Cout, int M, int N, int K, int Nout,
    const float* __restrict__ lng, const float* __restrict__ lnb)
{
    constexpr int MR = TM / 32;                 // 16-row m-frags per wave (wave owns TM/2 rows)
    constexpr int NR = TN / 32;                 // 16-col n-frags per wave (wave owns TN/2 cols)
    constexpr int EWA = A_F32 ? 4 : 2;
    constexpr int RBA = BK * EWA;               // A tile row bytes
    constexpr int RBB = BK * 2;                 // B tile row bytes
    constexpr int ABYTES = TM * RBA;
    constexpr int BBYTES = TN * RBB;
    constexpr int OPSA = ABYTES / 4096;         // gld16 instrs per thread (A)
    constexpr int OPSB = BBYTES / 4096;
    constexpr int VOPS = OPSA + OPSB;
    constexpr bool SWZA = (RBA >= 128);
    constexpr bool SWZB = (RBB >= 128);
    constexpr int KK = BK / 32;                 // MFMA k-substeps per round
    __shared__ __align__(16) char Alds[2][ABYTES];
    __shared__ __align__(16) char Blds[2][BBYTES];
    const int tid = threadIdx.x;
    const int w = tid >> 6, lane = tid & 63;

    // bijective XCD-chunked swizzle (nwg % 8 == 0 for all our shapes)
    const int nwg = gridDim.x;
    const int q = nwg >> 3;
    const int wg = (blockIdx.x & 7) * q + (blockIdx.x >> 3);
    const int nx = N / TN;
    const int bm = (wg / nx) * TM, bn = (wg % nx) * TN;

    const int wr = (w >> 1) * (TM / 2), wc = (w & 1) * (TN / 2);
    const int fr = lane & 15, fq = lane >> 4;
    const size_t KbB = (size_t)K * 2;
    const size_t KbA = (size_t)K * EWA;

    const char* Ab = (const char*)Aptr;
    const char* Bb = (const char*)Bt;
    const int lds0 = w * 1024;                  // wave-uniform dest offset, bytes

    f32x4 acc[MR][NR];
#pragma unroll
    for (int m = 0; m < MR; m++)
#pragma unroll
        for (int n = 0; n < NR; n++) acc[m][n] = (f32x4){0.f, 0.f, 0.f, 0.f};

    auto stageA = [&](int buf, int k0) {
        char* lA = Alds[buf];
#pragma unroll
        for (int i = 0; i < OPSA; i++) {
            const int o = i * 4096 + tid * 16;
            const int row = o / RBA;
            int col = o % RBA;
            if constexpr (SWZA) col ^= (row & 7) << 4;
            gld16(Ab + (size_t)(bm + row) * KbA + (size_t)k0 * EWA + col,
                  lA + i * 4096 + lds0);
        }
    };
    auto stageB = [&](int buf, int k0) {
        char* lB = Blds[buf];
#pragma unroll
        for (int i = 0; i < OPSB; i++) {
            const int o = i * 4096 + tid * 16;
            const int row = o / RBB;
            int col = o % RBB;
            if constexpr (SWZB) col ^= (row & 7) << 4;
            gld16(Bb + (size_t)(bn + row) * KbB + (size_t)k0 * 2 + col,
                  lB + i * 4096 + lds0);
        }
    };
    auto compute = [&](int buf) {
        const char* lA = Alds[buf];
        const char* lB = Blds[buf];
#pragma unroll
        for (int kk = 0; kk < KK; kk++) {        // kk-outer keeps frag regs small
            bf16x8 af[MR], bg[NR];
#pragma unroll
            for (int m = 0; m < MR; m++) {
                const int row = wr + m * 16 + fr;
                const int sw = SWZA ? ((row & 7) << 4) : 0;
                if constexpr (A_F32) {
                    const int b0 = row * RBA + kk * 128 + fq * 32;
                    float4 x0 = *(const float4*)(lA + (b0 ^ sw));
                    float4 x1 = *(const float4*)(lA + ((b0 + 16) ^ sw));
                    bf16x8 a;
                    a[0]=(__bf16)x0.x; a[1]=(__bf16)x0.y; a[2]=(__bf16)x0.z; a[3]=(__bf16)x0.w;
                    a[4]=(__bf16)x1.x; a[5]=(__bf16)x1.y; a[6]=(__bf16)x1.z; a[7]=(__bf16)x1.w;
                    af[m] = a;
                } else {
                    const int c = kk * 64 + fq * 16;
                    af[m] = *(const bf16x8*)(lA + row * RBA + (c ^ sw));
                }
            }
#pragma unroll
            for (int n = 0; n < NR; n++) {
                const int row = wc + n * 16 + fr;
                const int sw = SWZB ? ((row & 7) << 4) : 0;
                const int c = kk * 64 + fq * 16;
                bg[n] = *(const bf16x8*)(lB + row * RBB + (c ^ sw));
            }
#pragma unroll
            for (int m = 0; m < MR; m++)
#pragma unroll
                for (int n = 0; n < NR; n++)
                    acc[m][n] = __builtin_amdgcn_mfma_f32_16x16x32_bf16(af[m], bg[n], acc[m][n], 0, 0, 0);
        }
    };

    const int NT = K / BK;

    // ---- prologue: stage tile 0 into buf 0, full drain once ----
    stageA(0, 0); stageB(0, 0);
    asm volatile("s_waitcnt vmcnt(0) lgkmcnt(0)" ::: "memory");
    __builtin_amdgcn_s_barrier();
    __builtin_amdgcn_sched_barrier(0);

    for (int kt = 0; kt < NT; ++kt) {
        const int cur = kt & 1;
        const bool has_next = (kt + 1 < NT);
        if (has_next) {
            const int k0 = (kt + 1) * BK;
            stageA(cur ^ 1, k0); stageB(cur ^ 1, k0);
            waitv<VOPS>();          // current tile only; next stays in flight
        } else {
            waitv<0>();
        }
        __builtin_amdgcn_s_barrier();
        __builtin_amdgcn_sched_barrier(0);

        compute(cur);

        asm volatile("s_waitcnt lgkmcnt(0)" ::: "memory");
        __builtin_amdgcn_s_barrier();
        __builtin_amdgcn_sched_barrier(0);
    }

    if constexpr (LN64OUT) {
        // wc=0 waves hold cols 0..63 of their rows: col = n*16+fr (NR=4).
        if (wc == 0) {
#pragma unroll
            for (int m = 0; m < MR; m++) {
#pragma unroll
                for (int r = 0; r < 4; r++) {
                    float v[NR]; float s = 0.f, sq = 0.f;
#pragma unroll
                    for (int n = 0; n < NR; n++) {
                        v[n] = acc[m][n][r] + bias[n * 16 + fr];
                        s += v[n]; sq += v[n] * v[n];
                    }
#pragma unroll
                    for (int off = 8; off; off >>= 1) { s += __shfl_xor(s, off); sq += __shfl_xor(sq, off); }
                    float mean = s * (1.f / 64.f);
                    float var = sq * (1.f / 64.f) - mean * mean;
                    float rs = rsqrtf(var + 1e-5f);
                    int row = bm + wr + m * 16 + fq * 4 + r;
#pragma unroll
                    for (int n = 0; n < NR; n++) {
                        int col = n * 16 + fr;
                        ((float*)Cout)[(size_t)row * 64 + col] = (v[n] - mean) * rs * lng[col] + lnb[col];
                    }
                }
            }
        }
    } else {
#pragma unroll
        for (int m = 0; m < MR; m++) {
#pragma unroll
            for (int n = 0; n < NR; n++) {
                int col = bn + wc + n * 16 + fr;
                if (col < Nout) {
#pragma unroll
                    for (int r = 0; r < 4; r++) {
                        int row = bm + wr + m * 16 + fq * 4 + r;
                        float v = acc[m][n][r];
                        if (HAS_BIAS) v += bias[col];
                        if (HAS_RES)  v += res[(size_t)row * Nout + col];
                        if (OUT_BF16) ((unsigned short*)Cout)[(size_t)row * Nout + col] = f2bf(v);
                        else          ((float*)Cout)[(size_t)row * Nout + col] = v;
                    }
                }
            }
        }
    }
}

// ---------------- LayerNorm over 256, f32 -> bf16 ----------------
__global__ __launch_bounds__(256) void ln256(
    const float* __restrict__ x, const float* __restrict__ g,
    const float* __restrict__ b, unsigned short* __restrict__ out)
{
    int lane = threadIdx.x & 63, wid = threadIdx.x >> 6;
    size_t r = (size_t)blockIdx.x * 4 + wid;
    const float4 v = *(const float4*)&x[r * 256 + lane * 4];
    float s = v.x + v.y + v.z + v.w;
    float sq = v.x * v.x + v.y * v.y + v.z * v.z + v.w * v.w;
#pragma unroll
    for (int off = 32; off; off >>= 1) { s += __shfl_xor(s, off); sq += __shfl_xor(sq, off); }
    float mean = s * (1.f / 256.f);
    float var = sq * (1.f / 256.f) - mean * mean;
    float rs = rsqrtf(var + 1e-5f);
    float4 gv = *(const float4*)&g[lane * 4];
    float4 bv = *(const float4*)&b[lane * 4];
    ushort4 o;
    o.x = f2bf((v.x - mean) * rs * gv.x + bv.x);
    o.y = f2bf((v.y - mean) * rs * gv.y + bv.y);
    o.z = f2bf((v.z - mean) * rs * gv.z + bv.z);
    o.w = f2bf((v.w - mean) * rs * gv.w + bv.w);
    *(ushort4*)&out[r * 256 + lane * 4] = o;
}

// ---------------- Depthwise causal conv (K=4) + bias + silu, 8 d per thread ----------------
__global__ __launch_bounds__(256) void conv_silu8(
    const unsigned short* __restrict__ xz, const float* __restrict__ w,
    const float* __restrict__ cb, unsigned short* __restrict__ xc)
{
    int idx = blockIdx.x * 256 + threadIdx.x;     // NROWS*64 threads
    int d8 = (idx & 63) << 3;                     // lane -> d-group (coalesced)
    int l  = (idx >> 6) & 2047;
    int b  = idx >> 17;
    const unsigned short* base = xz + ((size_t)b * L_SEQ + l) * 1024 + d8;
    u16x8 t0 = {0,0,0,0,0,0,0,0}, t1 = t0, t2 = t0;
    u16x8 t3 = *(const u16x8*)base;
    if (l >= 1) t2 = *(const u16x8*)(base - 1024);
    if (l >= 2) t1 = *(const u16x8*)(base - 2048);
    if (l >= 3) t0 = *(const u16x8*)(base - 3072);
    u16x8 o;
#pragma unroll
    for (int j = 0; j < 8; j++) {
        float4 wv = *(const float4*)&w[(d8 + j) * 4];
        float acc = cb[d8 + j];
        acc = fmaf(bf2f(t0[j]), wv.x, acc);
        acc = fmaf(bf2f(t1[j]), wv.y, acc);
        acc = fmaf(bf2f(t2[j]), wv.z, acc);
        acc = fmaf(bf2f(t3[j]), wv.w, acc);
        o[j] = f2bf(acc * sigmoidf_(acc));
    }
    *(u16x8*)&xc[((size_t)b * L_SEQ + l) * 512 + d8] = o;
}

// ---------------- Chunked selective scan (dt fused in-register; P stored as
// scalar Tsum per (b,c,d) -- P[n]=exp2(Tsum*a2[n]) is recomputed in pass2) ----------------
__global__ __launch_bounds__(256) void scan_pass1(
    const unsigned short* __restrict__ xc, const float* __restrict__ xdbl,
    const float* __restrict__ Wdt, const float* __restrict__ bdt,
    const float* __restrict__ Alog,
    float* __restrict__ Tbuf, float* __restrict__ Sbuf)
{
    __shared__ float xs[T_CH][32];   // [t][0:16]=dt-proj inputs, [16:32]=B
    int idx = blockIdx.x * 256 + threadIdx.x;
    int d = idx & 511;
    int c = (idx >> 9) & (C_CH - 1);
    int b = idx >> 14;
    size_t r0 = (size_t)b * L_SEQ + (size_t)c * T_CH;
#pragma unroll
    for (int ii = 0; ii < 2; ii++) {
        int i = threadIdx.x + ii * 256, row = i >> 3, qq = i & 7;
        *(float4*)&xs[row][qq * 4] = *(const float4*)&xdbl[(r0 + row) * 48 + qq * 4];
    }
    __syncthreads();

    float wdt[16];
#pragma unroll
    for (int j = 0; j < 16; j++) wdt[j] = Wdt[j * 512 + d];
    const float bd = bdt[d];

    float a[16], a2[16], S[16];
#pragma unroll
    for (int n = 0; n < 16; n++) a[n] = -__expf(Alog[d * 16 + n]);
#pragma unroll
    for (int n = 0; n < 16; n++) a2[n] = a[n] * LOG2E;
#pragma unroll
    for (int n = 0; n < 16; n++) S[n] = 0.f;
    bool pow_ok = true;
#pragma unroll
    for (int n = 1; n < 16; n++)
        pow_ok = pow_ok && (fabsf(a[n] - (n + 1) * a[0]) <= 1e-3f * (n + 1) * fabsf(a[0]));
    const float a0l2 = a[0] * LOG2E;
    float Tsum = 0.f;

    if (pow_ok) {
        for (int t = 0; t < T_CH; t++) {
            float dtr = bd;
#pragma unroll
            for (int j = 0; j < 16; j++) dtr = fmaf(xs[t][j], wdt[j], dtr);
            float dtv = (dtr > 20.f) ? dtr : __logf(1.f + __expf(dtr));
            float u = bf2f(xc[(r0 + t) * 512 + d]);
            float dtu = dtv * u;
            Tsum += dtv;
            float e1 = EXP2F(dtv * a0l2), e2 = e1 * e1;
            S[0] = fmaf(e1, S[0], dtu * xs[t][16]);
            S[1] = fmaf(e2, S[1], dtu * xs[t][17]);
            float pm2 = e1, pm1 = e2;
#pragma unroll
            for (int n = 2; n < 16; n++) {
                float cur = pm2 * e2;
                S[n] = fmaf(cur, S[n], dtu * xs[t][16 + n]);
                pm2 = pm1; pm1 = cur;
            }
        }
    } else {
        for (int t = 0; t < T_CH; t++) {
            float dtr = bd;
#pragma unroll
            for (int j = 0; j < 16; j++) dtr = fmaf(xs[t][j], wdt[j], dtr);
            float dtv = (dtr > 20.f) ? dtr : __logf(1.f + __expf(dtr));
            float u = bf2f(xc[(r0 + t) * 512 + d]);
            float dtu = dtv * u;
            Tsum += dtv;
#pragma unroll
            for (int n = 0; n < 16; n++) {
                float dA = EXP2F(dtv * a2[n]);
                S[n] = fmaf(dA, S[n], dtu * xs[t][16 + n]);
            }
        }
    }
    Tbuf[idx] = Tsum;
    size_t o = (size_t)idx * 16;
#pragma unroll
    for (int qq = 0; qq < 4; qq++)
        *(float4*)&Sbuf[o + qq * 4] = make_float4(S[qq*4], S[qq*4+1], S[qq*4+2], S[qq*4+3]);
}

__global__ __launch_bounds__(256) void scan_pass2(
    const float* __restrict__ Tbuf, const float* __restrict__ Alog,
    float* __restrict__ Sbuf)
{
    int g = blockIdx.x * 256 + threadIdx.x;
    int nd = g & 8191;
    int b = g >> 13;
    int d = nd >> 4, n = nd & 15;
    const float a2 = -__expf(Alog[d * 16 + n]) * LOG2E;
    float H = 0.f;
    for (int c = 0; c < C_CH; c++) {
        size_t base = (size_t)(b * C_CH + c);
        float T = Tbuf[base * 512 + d];
        float P = EXP2F(T * a2);
        size_t idx = base * 8192 + nd;
        float S = Sbuf[idx];
        float Hn = fmaf(P, H, S);
        Sbuf[idx] = H;
        H = Hn;
    }
}

__global__ __launch_bounds__(256) void scan_pass3(
    const unsigned short* __restrict__ xcin, const unsigned short* __restrict__ xz,
    const float* __restrict__ xdbl, const float* __restrict__ Wdt,
    const float* __restrict__ bdt, const float* __restrict__ Alog,
    const float* __restrict__ Dsk, const float* __restrict__ Sbuf,
    unsigned short* __restrict__ y)
{
    __shared__ float xs[T_CH][48];   // [t][0:16]=dt-in, [16:32]=B, [32:48]=C
    int idx = blockIdx.x * 256 + threadIdx.x;
    int d = idx & 511;
    int c = (idx >> 9) & (C_CH - 1);
    int b = idx >> 14;
    size_t r0 = (size_t)b * L_SEQ + (size_t)c * T_CH;
#pragma unroll
    for (int ii = 0; ii < 3; ii++) {
        int i = threadIdx.x + ii * 256, row = i / 12, qq = i % 12;
        *(float4*)&xs[row][qq * 4] = *(const float4*)&xdbl[(r0 + row) * 48 + qq * 4];
    }
    __syncthreads();

    float wdt[16];
#pragma unroll
    for (int j = 0; j < 16; j++) wdt[j] = Wdt[j * 512 + d];
    const float bd = bdt[d];

    float a[16], a2[16], h[16];
#pragma unroll
    for (int n = 0; n < 16; n++) a[n] = -__expf(Alog[d * 16 + n]);
#pragma unroll
    for (int n = 0; n < 16; n++) a2[n] = a[n] * LOG2E;
    {
        size_t o = (size_t)idx * 16;
#pragma unroll
        for (int qq = 0; qq < 4; qq++) {
            float4 v = *(const float4*)&Sbuf[o + qq * 4];
            h[qq*4] = v.x; h[qq*4+1] = v.y; h[qq*4+2] = v.z; h[qq*4+3] = v.w;
        }
    }
    bool pow_ok = true;
#pragma unroll
    for (int n = 1; n < 16; n++)
        pow_ok = pow_ok && (fabsf(a[n] - (n + 1) * a[0]) <= 1e-3f * (n + 1) * fabsf(a[0]));
    const float a0l2 = a[0] * LOG2E;
    const float Dv = Dsk[d];

    if (pow_ok) {
        for (int t = 0; t < T_CH; t++) {
            size_t ridx = (r0 + t) * 512 + d;
            float dtr = bd;
#pragma unroll
            for (int j = 0; j < 16; j++) dtr = fmaf(xs[t][j], wdt[j], dtr);
            float dtv = (dtr > 20.f) ? dtr : __logf(1.f + __expf(dtr));
            float u = bf2f(xcin[ridx]);
            float dtu = dtv * u;
            float e1 = EXP2F(dtv * a0l2), e2 = e1 * e1;
            float yv = 0.f;
            h[0] = fmaf(e1, h[0], dtu * xs[t][16]);  yv = fmaf(h[0], xs[t][32], yv);
            h[1] = fmaf(e2, h[1], dtu * xs[t][17]);  yv = fmaf(h[1], xs[t][33], yv);
            float pm2 = e1, pm1 = e2;
#pragma unroll
            for (int n = 2; n < 16; n++) {
                float cur = pm2 * e2;
                h[n] = fmaf(cur, h[n], dtu * xs[t][16 + n]);
                yv = fmaf(h[n], xs[t][32 + n], yv);
                pm2 = pm1; pm1 = cur;
            }
            yv = fmaf(u, Dv, yv);
            float z = bf2f(xz[(r0 + t) * 1024 + 512 + d]);
            y[ridx] = f2bf(yv * z * sigmoidf_(z));
        }
    } else {
        for (int t = 0; t < T_CH; t++) {
            size_t ridx = (r0 + t) * 512 + d;
            float dtr = bd;
#pragma unroll
            for (int j = 0; j < 16; j++) dtr = fmaf(xs[t][j], wdt[j], dtr);
            float dtv = (dtr > 20.f) ? dtr : __logf(1.f + __expf(dtr));
            float u = bf2f(xcin[ridx]);
            float dtu = dtv * u;
            float yv = 0.f;
#pragma unroll
            for (int n = 0; n < 16; n++) {
                float dA = EXP2F(dtv * a2[n]);
                h[n] = fmaf(dA, h[n], dtu * xs[t][16 + n]);
                yv = fmaf(h[n], xs[t][32 + n], yv);
            }
            yv = fmaf(u, Dv, yv);
            float z = bf2f(xz[(r0 + t) * 1024 + 512 + d]);
            y[ridx] = f2bf(yv * z * sigmoidf_(z));
        }
    }
}

extern "C" void kernel_launch(void* const* d_in, const int* in_sizes, int n_in,
                              void* d_out, int out_size, void* d_ws, size_t ws_size,
                              hipStream_t stream)
{
    const float* z_t     = (const float*)d_in[0];
    const float* W_in    = (const float*)d_in[1];
    const float* b_in    = (const float*)d_in[2];
    const float* ln_g    = (const float*)d_in[3];
    const float* ln_b    = (const float*)d_in[4];
    const float* W_inpr  = (const float*)d_in[5];
    const float* conv_w  = (const float*)d_in[6];
    const float* conv_b  = (const float*)d_in[7];
    const float* W_xproj = (const float*)d_in[8];
    const float* W_dt    = (const float*)d_in[9];
    const float* b_dt    = (const float*)d_in[10];
    const float* A_log   = (const float*)d_in[11];
    const float* D_skip  = (const float*)d_in[12];
    const float* W_out   = (const float*)d_in[13];
    const float* W_outp  = (const float*)d_in[14];
    const float* b_outp  = (const float*)d_in[15];
    const float* lno_g   = (const float*)d_in[16];
    const float* lno_b   = (const float*)d_in[17];
    float* out           = (float*)d_out;

    // Workspace (~119 MB + weights)
    char* p = (char*)d_ws;
    float*          x    = (float*)p;          p += (size_t)NROWS * DMODEL * 4;      // 32 MB
    unsigned short* xn   = (unsigned short*)p; p += (size_t)NROWS * DMODEL * 2;      // 16 MB
    unsigned short* xc   = (unsigned short*)p; p += (size_t)NROWS * DINNER * 2;      // 32 MB
    unsigned short* xz   = (unsigned short*)p; p += (size_t)NROWS * 1024 * 2;        // 64 MB
    float*          xdbl = (float*)p;          p += (size_t)NROWS * 48 * 4;          // 6.3 MB
    float*          Pregion = (float*)p;       p += (size_t)BATCH * C_CH * DINNER * 16 * 4; // 16.8
    float*          Sbuf = (float*)p;          p += (size_t)BATCH * C_CH * DINNER * 16 * 4; // 16.8
    unsigned short* WinT  = (unsigned short*)p; p += (size_t)256 * 1088 * 2;
    unsigned short* WipT  = (unsigned short*)p; p += (size_t)2 * 1024 * 256 * 2;
    unsigned short* WoutT = (unsigned short*)p; p += (size_t)2 * 256 * 512 * 2;
    unsigned short* WxpT  = (unsigned short*)p; p += (size_t)2 * 128 * 512 * 2;
    unsigned short* WopT  = (unsigned short*)p; p += (size_t)128 * 256 * 2;
    // alias (timeline-disjoint):
    float* Tbuf = Pregion;   // 1 MB: pass1 -> pass2, per layer

    // prep: all weight transposes in ONE launch
    wtrans_all<<<4800, 256, 0, stream>>>(W_in, W_inpr, W_out, W_xproj, W_outp,
                                         WinT, WipT, WoutT, WxpT, WopT);

    // x = z_t @ W_in + b_in   (R4 proven config: TM=64/TN=128/BK=64, 64KB LDS)
    gemm_bf16<64, 128, 64, true, true, false, false, false><<<(NROWS / 64) * (256 / 128), 256, 0, stream>>>(
        z_t, WinT, b_in, nullptr, x, NROWS, 256, 1088, 256, nullptr, nullptr);

    for (int layer = 0; layer < 2; ++layer) {
        ln256<<<NROWS / 4, 256, 0, stream>>>(x, ln_g + layer * 256, ln_b + layer * 256, xn);
        gemm_bf16<128, 128, 32, false, false, false, true, false><<<(NROWS / 128) * (1024 / 128), 256, 0, stream>>>(
            xn, WipT + (size_t)layer * 1024 * 256, nullptr, nullptr, xz, NROWS, 1024, 256, 1024, nullptr, nullptr);
        conv_silu8<<<NROWS * 64 / 256, 256, 0, stream>>>(
            xz, conv_w + layer * 512 * 4, conv_b + layer * 512, xc);
        gemm_bf16<64, 128, 64, false, false, false, false, false><<<(NROWS / 64) * (128 / 128), 256, 0, stream>>>(
            xc, WxpT + (size_t)layer * 128 * 512, nullptr, nullptr, xdbl, NROWS, 128, 512, 48, nullptr, nullptr);

        const float* Al_l  = A_log + layer * 512 * 16;
        const float* Wdt_l = W_dt + layer * 16 * 512;
        const float* bdt_l = b_dt + layer * 512;
        scan_pass1<<<BATCH * C_CH * DINNER / 256, 256, 0, stream>>>(
            xc, xdbl, Wdt_l, bdt_l, Al_l, Tbuf, Sbuf);
        scan_pass2<<<BATCH * DINNER * 16 / 256, 256, 0, stream>>>(Tbuf, Al_l, Sbuf);
        scan_pass3<<<BATCH * C_CH * DINNER / 256, 256, 0, stream>>>(
            xc, xz, xdbl, Wdt_l, bdt_l, Al_l, D_skip + layer * 512, Sbuf, xc);

        if (layer == 0) {
            gemm_bf16<64, 128, 64, false, false, true, false, false><<<(NROWS / 64) * (256 / 128), 256, 0, stream>>>(
                xc, WoutT, nullptr, x, x, NROWS, 256, 512, 256, nullptr, nullptr);
        } else {
            // final residual add, emitted as bf16 directly (feeds out-proj GEMM)
            gemm_bf16<64, 128, 64, false, false, true, true, false><<<(NROWS / 64) * (256 / 128), 256, 0, stream>>>(
                xc, WoutT + (size_t)256 * 512, nullptr, x, xn, NROWS, 256, 512, 256, nullptr, nullptr);
        }
    }

    // out-proj via MFMA with the final LayerNorm(64) fused in the epilogue
    gemm_bf16<64, 128, 32, false, true, false, false, true><<<(NROWS / 64) * (128 / 128), 256, 0, stream>>>(
        xn, WopT, b_outp, nullptr, out, NROWS, 128, 256, 64, lno_g, lno_b);
}

// Round 9
// 526.557 us; speedup vs baseline: 1.0972x; 1.0077x over previous
//
#include <hip/hip_runtime.h>
#include <hip/hip_bf16.h>
#include <math.h>
#include <stdint.h>

#define L_SEQ 2048
#define BATCH 16
#define NROWS (BATCH * L_SEQ)   // 32768
#define DMODEL 256
#define DINNER 512
#define C_CH 32                  // chunks per sequence
#define T_CH 64                  // steps per chunk
#define LOG2E 1.4426950408889634f

typedef __attribute__((ext_vector_type(8))) __bf16 bf16x8;
typedef __attribute__((ext_vector_type(4))) float f32x4;
typedef __attribute__((ext_vector_type(8))) unsigned short u16x8;
typedef __attribute__((address_space(1))) const uint32_t gu32;
typedef __attribute__((address_space(3))) uint32_t lu32;

#if __has_builtin(__builtin_amdgcn_exp2f)
#define EXP2F __builtin_amdgcn_exp2f
#else
#define EXP2F exp2f
#endif

__device__ __forceinline__ float sigmoidf_(float x) { return 1.f / (1.f + __expf(-x)); }

__device__ __forceinline__ unsigned short f2bf(float f) {
    union { float f; uint32_t u; } v; v.f = f;
    uint32_t r = v.u + 0x7FFF + ((v.u >> 16) & 1);
    return (unsigned short)(r >> 16);
}
__device__ __forceinline__ float bf2f(unsigned short h) {
    union { uint32_t u; float f; } v; v.u = ((uint32_t)h) << 16;
    return v.f;
}

__device__ __forceinline__ void gld16(const void* g, void* l) {
    __builtin_amdgcn_global_load_lds((gu32*)g, (lu32*)l, 16, 0, 0);
}

template <int N> __device__ __forceinline__ void waitv() {
    if constexpr (N == 0)       asm volatile("s_waitcnt vmcnt(0)" ::: "memory");
    else if constexpr (N == 3)  asm volatile("s_waitcnt vmcnt(3)" ::: "memory");
    else if constexpr (N == 4)  asm volatile("s_waitcnt vmcnt(4)" ::: "memory");
    else if constexpr (N == 6)  asm volatile("s_waitcnt vmcnt(6)" ::: "memory");
    else if constexpr (N == 8)  asm volatile("s_waitcnt vmcnt(8)" ::: "memory");
    else if constexpr (N == 16) asm volatile("s_waitcnt vmcnt(16)" ::: "memory");
}

// ---------------- prep: ALL weight transposes in one launch (8 -> 1 dispatch) ----
// seg layout (blocks): [0,1088) W_in | [1088,3136) W_inpr l0/l1 | [3136,4160)
// W_out l0/l1 | [4160,4672) W_xproj l0/l1 (pad 48->128) | [4672,4800) W_outp (pad 64->128)
__global__ __launch_bounds__(256) void wtrans_all(
    const float* __restrict__ W_in, const float* __restrict__ W_inpr,
    const float* __restrict__ W_out, const float* __restrict__ W_xproj,
    const float* __restrict__ W_outp,
    unsigned short* __restrict__ WinT, unsigned short* __restrict__ WipT,
    unsigned short* __restrict__ WoutT, unsigned short* __restrict__ WxpT,
    unsigned short* __restrict__ WopT)
{
    const int bid = blockIdx.x, tid = threadIdx.x;
    if (bid < 1088) {                              // W_in: K=1088, N=256
        int idx = bid * 256 + tid;
        int n = idx / 1088, k = idx % 1088;
        WinT[idx] = f2bf(W_in[(size_t)k * 256 + n]);
    } else if (bid < 3136) {                       // W_inpr: K=256, N=1024 (x2)
        int l = (bid - 1088) >> 10;
        int idx = ((bid - 1088) & 1023) * 256 + tid;
        int n = idx >> 8, k = idx & 255;
        WipT[(size_t)l * 262144 + idx] = f2bf(W_inpr[(size_t)l * 262144 + (size_t)k * 1024 + n]);
    } else if (bid < 4160) {                       // W_out: K=512, N=256 (x2)
        int l = (bid - 3136) >> 9;
        int idx = ((bid - 3136) & 511) * 256 + tid;
        int n = idx >> 9, k = idx & 511;
        WoutT[(size_t)l * 131072 + idx] = f2bf(W_out[(size_t)l * 131072 + (size_t)k * 256 + n]);
    } else if (bid < 4672) {                       // W_xproj: K=512, Nreal=48, Npad=128 (x2)
        int l = (bid - 4160) >> 8;
        int idx = ((bid - 4160) & 255) * 256 + tid;
        int n = idx >> 9, k = idx & 511;
        WxpT[(size_t)l * 65536 + idx] =
            (n < 48) ? f2bf(W_xproj[(size_t)l * (512 * 48) + (size_t)k * 48 + n]) : (unsigned short)0;
    } else {                                       // W_outp: K=256, Nreal=64, Npad=128
        int idx = (bid - 4672) * 256 + tid;
        int n = idx >> 8, k = idx & 255;
        WopT[idx] = (n < 64) ? f2bf(W_outp[(size_t)k * 64 + n]) : (unsigned short)0;
    }
}

// ---------------- bf16 MFMA GEMM, double-buffered LDS + COUNTED vmcnt ----------------
// C(M x Nout) = A(MxK) @ Bt(NxK)^T.  Tile TM x TN; BK in {32, 64}.
// R1-R8 model (validated on R4 win / R6 loss / R7 loss / R8 win):
//   wall = slots x ~2.2us, slots = blocks/CU x NT / resident;
//   resident = min(LDS-cap, VGPR-cap, grid-cap), must be >= 2 to stream (R6).
// Levers that work: fewer rounds (BK=64), fewer launches, epilogue fusion.
// Levers that fail: depth>2 (R2), split-K (R3), reg-B (R5), fat 1-resident
// tiles (R6), VGPR-heavy TN=256 (R7).
// Both operands prefetched one full round ahead via LDS (R5). Row-bytes >= 128
// -> XOR swizzle (col ^= (row&7)<<4) on pre-swizzled source + frag read (rule 21).
// LN64OUT: fuse final LayerNorm(64) into the epilogue (Nout=64, NR=4: wc=0
// waves hold each row's full 64 cols; shfl_xor masks 1/2/4/8 stay in fr-group).
template <int TM, int TN, int BK, bool A_F32, bool HAS_BIAS, bool HAS_RES, bool OUT_BF16, bool LN64OUT>
__global__ __launch_bounds__(256) void gemm_bf16(
    const void* __restrict__ Aptr, const unsigned short* __restrict__ Bt,
    const float* __restrict__ bias, const float* __restrict__ res,
    void* __restrict__ Cout, int M, int N, int K, int Nout,
    const float* __restrict__ lng, const float* __restrict__ lnb)
{
    constexpr int MR = TM / 32;                 // 16-row m-frags per wave (wave owns TM/2 rows)
    constexpr int NR = TN / 32;                 // 16-col n-frags per wave (wave owns TN/2 cols)
    constexpr int EWA = A_F32 ? 4 : 2;
    constexpr int RBA = BK * EWA;               // A tile row bytes
    constexpr int RBB = BK * 2;                 // B tile row bytes
    constexpr int ABYTES = TM * RBA;
    constexpr int BBYTES = TN * RBB;
    constexpr int OPSA = ABYTES / 4096;         // gld16 instrs per thread (A)
    constexpr int OPSB = BBYTES / 4096;
    constexpr int VOPS = OPSA + OPSB;
    constexpr bool SWZA = (RBA >= 128);
    constexpr bool SWZB = (RBB >= 128);
    constexpr int KK = BK / 32;                 // MFMA k-substeps per round
    __shared__ __align__(16) char Alds[2][ABYTES];
    __shared__ __align__(16) char Blds[2][BBYTES];
    const int tid = threadIdx.x;
    const int w = tid >> 6, lane = tid & 63;

    // bijective XCD-chunked swizzle (nwg % 8 == 0 for all our shapes)
    const int nwg = gridDim.x;
    const int q = nwg >> 3;
    const int wg = (blockIdx.x & 7) * q + (blockIdx.x >> 3);
    const int nx = N / TN;
    const int bm = (wg / nx) * TM, bn = (wg % nx) * TN;

    const int wr = (w >> 1) * (TM / 2), wc = (w & 1) * (TN / 2);
    const int fr = lane & 15, fq = lane >> 4;
    const size_t KbB = (size_t)K * 2;
    const size_t KbA = (size_t)K * EWA;

    const char* Ab = (const char*)Aptr;
    const char* Bb = (const char*)Bt;
    const int lds0 = w * 1024;                  // wave-uniform dest offset, bytes

    f32x4 acc[MR][NR];
#pragma unroll
    for (int m = 0; m < MR; m++)
#pragma unroll
        for (int n = 0; n < NR; n++) acc[m][n] = (f32x4){0.f, 0.f, 0.f, 0.f};

    auto stageA = [&](int buf, int k0) {
        char* lA = Alds[buf];
#pragma unroll
        for (int i = 0; i < OPSA; i++) {
            const int o = i * 4096 + tid * 16;
            const int row = o / RBA;
            int col = o % RBA;
            if constexpr (SWZA) col ^= (row & 7) << 4;
            gld16(Ab + (size_t)(bm + row) * KbA + (size_t)k0 * EWA + col,
                  lA + i * 4096 + lds0);
        }
    };
    auto stageB = [&](int buf, int k0) {
        char* lB = Blds[buf];
#pragma unroll
        for (int i = 0; i < OPSB; i++) {
            const int o = i * 4096 + tid * 16;
            const int row = o / RBB;
            int col = o % RBB;
            if constexpr (SWZB) col ^= (row & 7) << 4;
            gld16(Bb + (size_t)(bn + row) * KbB + (size_t)k0 * 2 + col,
                  lB + i * 4096 + lds0);
        }
    };
    auto compute = [&](int buf) {
        const char* lA = Alds[buf];
        const char* lB = Blds[buf];
#pragma unroll
        for (int kk = 0; kk < KK; kk++) {        // kk-outer keeps frag regs small
            bf16x8 af[MR], bg[NR];
#pragma unroll
            for (int m = 0; m < MR; m++) {
                const int row = wr + m * 16 + fr;
                const int sw = SWZA ? ((row & 7) << 4) : 0;
                if constexpr (A_F32) {
                    const int b0 = row * RBA + kk * 128 + fq * 32;
                    float4 x0 = *(const float4*)(lA + (b0 ^ sw));
                    float4 x1 = *(const float4*)(lA + ((b0 + 16) ^ sw));
                    bf16x8 a;
                    a[0]=(__bf16)x0.x; a[1]=(__bf16)x0.y; a[2]=(__bf16)x0.z; a[3]=(__bf16)x0.w;
                    a[4]=(__bf16)x1.x; a[5]=(__bf16)x1.y; a[6]=(__bf16)x1.z; a[7]=(__bf16)x1.w;
                    af[m] = a;
                } else {
                    const int c = kk * 64 + fq * 16;
                    af[m] = *(const bf16x8*)(lA + row * RBA + (c ^ sw));
                }
            }
#pragma unroll
            for (int n = 0; n < NR; n++) {
                const int row = wc + n * 16 + fr;
                const int sw = SWZB ? ((row & 7) << 4) : 0;
                const int c = kk * 64 + fq * 16;
                bg[n] = *(const bf16x8*)(lB + row * RBB + (c ^ sw));
            }
#pragma unroll
            for (int m = 0; m < MR; m++)
#pragma unroll
                for (int n = 0; n < NR; n++)
                    acc[m][n] = __builtin_amdgcn_mfma_f32_16x16x32_bf16(af[m], bg[n], acc[m][n], 0, 0, 0);
        }
    };

    const int NT = K / BK;

    // ---- prologue: stage tile 0 into buf 0, full drain once ----
    stageA(0, 0); stageB(0, 0);
    asm volatile("s_waitcnt vmcnt(0) lgkmcnt(0)" ::: "memory");
    __builtin_amdgcn_s_barrier();
    __builtin_amdgcn_sched_barrier(0);

    for (int kt = 0; kt < NT; ++kt) {
        const int cur = kt & 1;
        const bool has_next = (kt + 1 < NT);
        if (has_next) {
            const int k0 = (kt + 1) * BK;
            stageA(cur ^ 1, k0); stageB(cur ^ 1, k0);
            waitv<VOPS>();          // current tile only; next stays in flight
        } else {
            waitv<0>();
        }
        __builtin_amdgcn_s_barrier();
        __builtin_amdgcn_sched_barrier(0);

        compute(cur);

        asm volatile("s_waitcnt lgkmcnt(0)" ::: "memory");
        __builtin_amdgcn_s_barrier();
        __builtin_amdgcn_sched_barrier(0);
    }

    if constexpr (LN64OUT) {
        // wc=0 waves hold cols 0..63 of their rows: col = n*16+fr (NR=4).
        if (wc == 0) {
#pragma unroll
            for (int m = 0; m < MR; m++) {
#pragma unroll
                for (int r = 0; r < 4; r++) {
                    float v[NR]; float s = 0.f, sq = 0.f;
#pragma unroll
                    for (int n = 0; n < NR; n++) {
                        v[n] = acc[m][n][r] + bias[n * 16 + fr];
                        s += v[n]; sq += v[n] * v[n];
                    }
#pragma unroll
                    for (int off = 8; off; off >>= 1) { s += __shfl_xor(s, off); sq += __shfl_xor(sq, off); }
                    float mean = s * (1.f / 64.f);
                    float var = sq * (1.f / 64.f) - mean * mean;
                    float rs = rsqrtf(var + 1e-5f);
                    int row = bm + wr + m * 16 + fq * 4 + r;
#pragma unroll
                    for (int n = 0; n < NR; n++) {
                        int col = n * 16 + fr;
                        ((float*)Cout)[(size_t)row * 64 + col] = (v[n] - mean) * rs * lng[col] + lnb[col];
                    }
                }
            }
        }
    } else {
#pragma unroll
        for (int m = 0; m < MR; m++) {
#pragma unroll
            for (int n = 0; n < NR; n++) {
                int col = bn + wc + n * 16 + fr;
                if (col < Nout) {
#pragma unroll
                    for (int r = 0; r < 4; r++) {
                        int row = bm + wr + m * 16 + fq * 4 + r;
                        float v = acc[m][n][r];
                        if (HAS_BIAS) v += bias[col];
                        if (HAS_RES)  v += res[(size_t)row * Nout + col];
                        if (OUT_BF16) ((unsigned short*)Cout)[(size_t)row * Nout + col] = f2bf(v);
                        else          ((float*)Cout)[(size_t)row * Nout + col] = v;
                    }
                }
            }
        }
    }
}

// ---------------- LayerNorm over 256, f32 -> bf16 ----------------
__global__ __launch_bounds__(256) void ln256(
    const float* __restrict__ x, const float* __restrict__ g,
    const float* __restrict__ b, unsigned short* __restrict__ out)
{
    int lane = threadIdx.x & 63, wid = threadIdx.x >> 6;
    size_t r = (size_t)blockIdx.x * 4 + wid;
    const float4 v = *(const float4*)&x[r * 256 + lane * 4];
    float s = v.x + v.y + v.z + v.w;
    float sq = v.x * v.x + v.y * v.y + v.z * v.z + v.w * v.w;
#pragma unroll
    for (int off = 32; off; off >>= 1) { s += __shfl_xor(s, off); sq += __shfl_xor(sq, off); }
    float mean = s * (1.f / 256.f);
    float var = sq * (1.f / 256.f) - mean * mean;
    float rs = rsqrtf(var + 1e-5f);
    float4 gv = *(const float4*)&g[lane * 4];
    float4 bv = *(const float4*)&b[lane * 4];
    ushort4 o;
    o.x = f2bf((v.x - mean) * rs * gv.x + bv.x);
    o.y = f2bf((v.y - mean) * rs * gv.y + bv.y);
    o.z = f2bf((v.z - mean) * rs * gv.z + bv.z);
    o.w = f2bf((v.w - mean) * rs * gv.w + bv.w);
    *(ushort4*)&out[r * 256 + lane * 4] = o;
}

// ---------------- Depthwise causal conv (K=4) + bias + silu, 8 d per thread ----------------
__global__ __launch_bounds__(256) void conv_silu8(
    const unsigned short* __restrict__ xz, const float* __restrict__ w,
    const float* __restrict__ cb, unsigned short* __restrict__ xc)
{
    int idx = blockIdx.x * 256 + threadIdx.x;     // NROWS*64 threads
    int d8 = (idx & 63) << 3;                     // lane -> d-group (coalesced)
    int l  = (idx >> 6) & 2047;
    int b  = idx >> 17;
    const unsigned short* base = xz + ((size_t)b * L_SEQ + l) * 1024 + d8;
    u16x8 t0 = {0,0,0,0,0,0,0,0}, t1 = t0, t2 = t0;
    u16x8 t3 = *(const u16x8*)base;
    if (l >= 1) t2 = *(const u16x8*)(base - 1024);
    if (l >= 2) t1 = *(const u16x8*)(base - 2048);
    if (l >= 3) t0 = *(const u16x8*)(base - 3072);
    u16x8 o;
#pragma unroll
    for (int j = 0; j < 8; j++) {
        float4 wv = *(const float4*)&w[(d8 + j) * 4];
        float acc = cb[d8 + j];
        acc = fmaf(bf2f(t0[j]), wv.x, acc);
        acc = fmaf(bf2f(t1[j]), wv.y, acc);
        acc = fmaf(bf2f(t2[j]), wv.z, acc);
        acc = fmaf(bf2f(t3[j]), wv.w, acc);
        o[j] = f2bf(acc * sigmoidf_(acc));
    }
    *(u16x8*)&xc[((size_t)b * L_SEQ + l) * 512 + d8] = o;
}

// ---------------- Chunked selective scan (dt fused in-register; P stored as
// scalar Tsum per (b,c,d) -- P[n]=exp2(Tsum*a2[n]) is recomputed in pass2) ----------------
__global__ __launch_bounds__(256) void scan_pass1(
    const unsigned short* __restrict__ xc, const float* __restrict__ xdbl,
    const float* __restrict__ Wdt, const float* __restrict__ bdt,
    const float* __restrict__ Alog,
    float* __restrict__ Tbuf, float* __restrict__ Sbuf)
{
    __shared__ float xs[T_CH][32];   // [t][0:16]=dt-proj inputs, [16:32]=B
    int idx = blockIdx.x * 256 + threadIdx.x;
    int d = idx & 511;
    int c = (idx >> 9) & (C_CH - 1);
    int b = idx >> 14;
    size_t r0 = (size_t)b * L_SEQ + (size_t)c * T_CH;
#pragma unroll
    for (int ii = 0; ii < 2; ii++) {
        int i = threadIdx.x + ii * 256, row = i >> 3, qq = i & 7;
        *(float4*)&xs[row][qq * 4] = *(const float4*)&xdbl[(r0 + row) * 48 + qq * 4];
    }
    __syncthreads();

    float wdt[16];
#pragma unroll
    for (int j = 0; j < 16; j++) wdt[j] = Wdt[j * 512 + d];
    const float bd = bdt[d];

    float a[16], a2[16], S[16];
#pragma unroll
    for (int n = 0; n < 16; n++) a[n] = -__expf(Alog[d * 16 + n]);
#pragma unroll
    for (int n = 0; n < 16; n++) a2[n] = a[n] * LOG2E;
#pragma unroll
    for (int n = 0; n < 16; n++) S[n] = 0.f;
    bool pow_ok = true;
#pragma unroll
    for (int n = 1; n < 16; n++)
        pow_ok = pow_ok && (fabsf(a[n] - (n + 1) * a[0]) <= 1e-3f * (n + 1) * fabsf(a[0]));
    const float a0l2 = a[0] * LOG2E;
    float Tsum = 0.f;

    if (pow_ok) {
        for (int t = 0; t < T_CH; t++) {
            float dtr = bd;
#pragma unroll
            for (int j = 0; j < 16; j++) dtr = fmaf(xs[t][j], wdt[j], dtr);
            float dtv = (dtr > 20.f) ? dtr : __logf(1.f + __expf(dtr));
            float u = bf2f(xc[(r0 + t) * 512 + d]);
            float dtu = dtv * u;
            Tsum += dtv;
            float e1 = EXP2F(dtv * a0l2), e2 = e1 * e1;
            S[0] = fmaf(e1, S[0], dtu * xs[t][16]);
            S[1] = fmaf(e2, S[1], dtu * xs[t][17]);
            float pm2 = e1, pm1 = e2;
#pragma unroll
            for (int n = 2; n < 16; n++) {
                float cur = pm2 * e2;
                S[n] = fmaf(cur, S[n], dtu * xs[t][16 + n]);
                pm2 = pm1; pm1 = cur;
            }
        }
    } else {
        for (int t = 0; t < T_CH; t++) {
            float dtr = bd;
#pragma unroll
            for (int j = 0; j < 16; j++) dtr = fmaf(xs[t][j], wdt[j], dtr);
            float dtv = (dtr > 20.f) ? dtr : __logf(1.f + __expf(dtr));
            float u = bf2f(xc[(r0 + t) * 512 + d]);
            float dtu = dtv * u;
            Tsum += dtv;
#pragma unroll
            for (int n = 0; n < 16; n++) {
                float dA = EXP2F(dtv * a2[n]);
                S[n] = fmaf(dA, S[n], dtu * xs[t][16 + n]);
            }
        }
    }
    Tbuf[idx] = Tsum;
    size_t o = (size_t)idx * 16;
#pragma unroll
    for (int qq = 0; qq < 4; qq++)
        *(float4*)&Sbuf[o + qq * 4] = make_float4(S[qq*4], S[qq*4+1], S[qq*4+2], S[qq*4+3]);
}

__global__ __launch_bounds__(256) void scan_pass2(
    const float* __restrict__ Tbuf, const float* __restrict__ Alog,
    float* __restrict__ Sbuf)
{
    int g = blockIdx.x * 256 + threadIdx.x;
    int nd = g & 8191;
    int b = g >> 13;
    int d = nd >> 4, n = nd & 15;
    const float a2 = -__expf(Alog[d * 16 + n]) * LOG2E;
    float H = 0.f;
    for (int c = 0; c < C_CH; c++) {
        size_t base = (size_t)(b * C_CH + c);
        float T = Tbuf[base * 512 + d];
        float P = EXP2F(T * a2);
        size_t idx = base * 8192 + nd;
        float S = Sbuf[idx];
        float Hn = fmaf(P, H, S);
        Sbuf[idx] = H;
        H = Hn;
    }
}

__global__ __launch_bounds__(256) void scan_pass3(
    const unsigned short* __restrict__ xcin, const unsigned short* __restrict__ xz,
    const float* __restrict__ xdbl, const float* __restrict__ Wdt,
    const float* __restrict__ bdt, const float* __restrict__ Alog,
    const float* __restrict__ Dsk, const float* __restrict__ Sbuf,
    unsigned short* __restrict__ y)
{
    __shared__ float xs[T_CH][48];   // [t][0:16]=dt-in, [16:32]=B, [32:48]=C
    int idx = blockIdx.x * 256 + threadIdx.x;
    int d = idx & 511;
    int c = (idx >> 9) & (C_CH - 1);
    int b = idx >> 14;
    size_t r0 = (size_t)b * L_SEQ + (size_t)c * T_CH;
#pragma unroll
    for (int ii = 0; ii < 3; ii++) {
        int i = threadIdx.x + ii * 256, row = i / 12, qq = i % 12;
        *(float4*)&xs[row][qq * 4] = *(const float4*)&xdbl[(r0 + row) * 48 + qq * 4];
    }
    __syncthreads();

    float wdt[16];
#pragma unroll
    for (int j = 0; j < 16; j++) wdt[j] = Wdt[j * 512 + d];
    const float bd = bdt[d];

    float a[16], a2[16], h[16];
#pragma unroll
    for (int n = 0; n < 16; n++) a[n] = -__expf(Alog[d * 16 + n]);
#pragma unroll
    for (int n = 0; n < 16; n++) a2[n] = a[n] * LOG2E;
    {
        size_t o = (size_t)idx * 16;
#pragma unroll
        for (int qq = 0; qq < 4; qq++) {
            float4 v = *(const float4*)&Sbuf[o + qq * 4];
            h[qq*4] = v.x; h[qq*4+1] = v.y; h[qq*4+2] = v.z; h[qq*4+3] = v.w;
        }
    }
    bool pow_ok = true;
#pragma unroll
    for (int n = 1; n < 16; n++)
        pow_ok = pow_ok && (fabsf(a[n] - (n + 1) * a[0]) <= 1e-3f * (n + 1) * fabsf(a[0]));
    const float a0l2 = a[0] * LOG2E;
    const float Dv = Dsk[d];

    if (pow_ok) {
        for (int t = 0; t < T_CH; t++) {
            size_t ridx = (r0 + t) * 512 + d;
            float dtr = bd;
#pragma unroll
            for (int j = 0; j < 16; j++) dtr = fmaf(xs[t][j], wdt[j], dtr);
            float dtv = (dtr > 20.f) ? dtr : __logf(1.f + __expf(dtr));
            float u = bf2f(xcin[ridx]);
            float dtu = dtv * u;
            float e1 = EXP2F(dtv * a0l2), e2 = e1 * e1;
            float yv = 0.f;
            h[0] = fmaf(e1, h[0], dtu * xs[t][16]);  yv = fmaf(h[0], xs[t][32], yv);
            h[1] = fmaf(e2, h[1], dtu * xs[t][17]);  yv = fmaf(h[1], xs[t][33], yv);
            float pm2 = e1, pm1 = e2;
#pragma unroll
            for (int n = 2; n < 16; n++) {
                float cur = pm2 * e2;
                h[n] = fmaf(cur, h[n], dtu * xs[t][16 + n]);
                yv = fmaf(h[n], xs[t][32 + n], yv);
                pm2 = pm1; pm1 = cur;
            }
            yv = fmaf(u, Dv, yv);
            float z = bf2f(xz[(r0 + t) * 1024 + 512 + d]);
            y[ridx] = f2bf(yv * z * sigmoidf_(z));
        }
    } else {
        for (int t = 0; t < T_CH; t++) {
            size_t ridx = (r0 + t) * 512 + d;
            float dtr = bd;
#pragma unroll
            for (int j = 0; j < 16; j++) dtr = fmaf(xs[t][j], wdt[j], dtr);
            float dtv = (dtr > 20.f) ? dtr : __logf(1.f + __expf(dtr));
            float u = bf2f(xcin[ridx]);
            float dtu = dtv * u;
            float yv = 0.f;
#pragma unroll
            for (int n = 0; n < 16; n++) {
                float dA = EXP2F(dtv * a2[n]);
                h[n] = fmaf(dA, h[n], dtu * xs[t][16 + n]);
                yv = fmaf(h[n], xs[t][32 + n], yv);
            }
            yv = fmaf(u, Dv, yv);
            float z = bf2f(xz[(r0 + t) * 1024 + 512 + d]);
            y[ridx] = f2bf(yv * z * sigmoidf_(z));
        }
    }
}

extern "C" void kernel_launch(void* const* d_in, const int* in_sizes, int n_in,
                              void* d_out, int out_size, void* d_ws, size_t ws_size,
                              hipStream_t stream)
{
    const float* z_t     = (const float*)d_in[0];
    const float* W_in    = (const float*)d_in[1];
    const float* b_in    = (const float*)d_in[2];
    const float* ln_g    = (const float*)d_in[3];
    const float* ln_b    = (const float*)d_in[4];
    const float* W_inpr  = (const float*)d_in[5];
    const float* conv_w  = (const float*)d_in[6];
    const float* conv_b  = (const float*)d_in[7];
    const float* W_xproj = (const float*)d_in[8];
    const float* W_dt    = (const float*)d_in[9];
    const float* b_dt    = (const float*)d_in[10];
    const float* A_log   = (const float*)d_in[11];
    const float* D_skip  = (const float*)d_in[12];
    const float* W_out   = (const float*)d_in[13];
    const float* W_outp  = (const float*)d_in[14];
    const float* b_outp  = (const float*)d_in[15];
    const float* lno_g   = (const float*)d_in[16];
    const float* lno_b   = (const float*)d_in[17];
    float* out           = (float*)d_out;

    // Workspace (~119 MB + weights)
    char* p = (char*)d_ws;
    float*          x    = (float*)p;          p += (size_t)NROWS * DMODEL * 4;      // 32 MB
    unsigned short* xn   = (unsigned short*)p; p += (size_t)NROWS * DMODEL * 2;      // 16 MB
    unsigned short* xc   = (unsigned short*)p; p += (size_t)NROWS * DINNER * 2;      // 32 MB
    unsigned short* xz   = (unsigned short*)p; p += (size_t)NROWS * 1024 * 2;        // 64 MB
    float*          xdbl = (float*)p;          p += (size_t)NROWS * 48 * 4;          // 6.3 MB
    float*          Pregion = (float*)p;       p += (size_t)BATCH * C_CH * DINNER * 16 * 4; // 16.8
    float*          Sbuf = (float*)p;          p += (size_t)BATCH * C_CH * DINNER * 16 * 4; // 16.8
    unsigned short* WinT  = (unsigned short*)p; p += (size_t)256 * 1088 * 2;
    unsigned short* WipT  = (unsigned short*)p; p += (size_t)2 * 1024 * 256 * 2;
    unsigned short* WoutT = (unsigned short*)p; p += (size_t)2 * 256 * 512 * 2;
    unsigned short* WxpT  = (unsigned short*)p; p += (size_t)2 * 128 * 512 * 2;
    unsigned short* WopT  = (unsigned short*)p; p += (size_t)128 * 256 * 2;
    // alias (timeline-disjoint):
    float* Tbuf = Pregion;   // 1 MB: pass1 -> pass2, per layer

    // prep: all weight transposes in ONE launch
    wtrans_all<<<4800, 256, 0, stream>>>(W_in, W_inpr, W_out, W_xproj, W_outp,
                                         WinT, WipT, WoutT, WxpT, WopT);

    // x = z_t @ W_in + b_in   (R4 proven config: TM=64/TN=128/BK=64, 64KB LDS)
    gemm_bf16<64, 128, 64, true, true, false, false, false><<<(NROWS / 64) * (256 / 128), 256, 0, stream>>>(
        z_t, WinT, b_in, nullptr, x, NROWS, 256, 1088, 256, nullptr, nullptr);

    for (int layer = 0; layer < 2; ++layer) {
        ln256<<<NROWS / 4, 256, 0, stream>>>(x, ln_g + layer * 256, ln_b + layer * 256, xn);
        // inproj: BK=64 (NT 8->4; the one K-heavy GEMM R4 left at BK=32)
        gemm_bf16<128, 128, 64, false, false, false, true, false><<<(NROWS / 128) * (1024 / 128), 256, 0, stream>>>(
            xn, WipT + (size_t)layer * 1024 * 256, nullptr, nullptr, xz, NROWS, 1024, 256, 1024, nullptr, nullptr);
        conv_silu8<<<NROWS * 64 / 256, 256, 0, stream>>>(
            xz, conv_w + layer * 512 * 4, conv_b + layer * 512, xc);
        gemm_bf16<64, 128, 64, false, false, false, false, false><<<(NROWS / 64) * (128 / 128), 256, 0, stream>>>(
            xc, WxpT + (size_t)layer * 128 * 512, nullptr, nullptr, xdbl, NROWS, 128, 512, 48, nullptr, nullptr);

        const float* Al_l  = A_log + layer * 512 * 16;
        const float* Wdt_l = W_dt + layer * 16 * 512;
        const float* bdt_l = b_dt + layer * 512;
        scan_pass1<<<BATCH * C_CH * DINNER / 256, 256, 0, stream>>>(
            xc, xdbl, Wdt_l, bdt_l, Al_l, Tbuf, Sbuf);
        scan_pass2<<<BATCH * DINNER * 16 / 256, 256, 0, stream>>>(Tbuf, Al_l, Sbuf);
        scan_pass3<<<BATCH * C_CH * DINNER / 256, 256, 0, stream>>>(
            xc, xz, xdbl, Wdt_l, bdt_l, Al_l, D_skip + layer * 512, Sbuf, xc);

        if (layer == 0) {
            gemm_bf16<64, 128, 64, false, false, true, false, false><<<(NROWS / 64) * (256 / 128), 256, 0, stream>>>(
                xc, WoutT, nullptr, x, x, NROWS, 256, 512, 256, nullptr, nullptr);
        } else {
            // final residual add, emitted as bf16 directly (feeds out-proj GEMM)
            gemm_bf16<64, 128, 64, false, false, true, true, false><<<(NROWS / 64) * (256 / 128), 256, 0, stream>>>(
                xc, WoutT + (size_t)256 * 512, nullptr, x, xn, NROWS, 256, 512, 256, nullptr, nullptr);
        }
    }

    // out-proj via MFMA (BK=64: NT 8->4) with the final LayerNorm(64) fused
    gemm_bf16<64, 128, 64, false, true, false, false, true><<<(NROWS / 64) * (128 / 128), 256, 0, stream>>>(
        xn, WopT, b_outp, nullptr, out, NROWS, 128, 256, 64, lno_g, lno_b);
}

// Round 10
// 507.547 us; speedup vs baseline: 1.1383x; 1.0375x over previous
//
#include <hip/hip_runtime.h>
#include <hip/hip_bf16.h>
#include <math.h>
#include <stdint.h>

#define L_SEQ 2048
#define BATCH 16
#define NROWS (BATCH * L_SEQ)   // 32768
#define DMODEL 256
#define DINNER 512
#define C_CH 32                  // chunks per sequence
#define T_CH 64                  // steps per chunk
#define LOG2E 1.4426950408889634f

typedef __attribute__((ext_vector_type(8))) __bf16 bf16x8;
typedef __attribute__((ext_vector_type(4))) float f32x4;
typedef __attribute__((ext_vector_type(8))) unsigned short u16x8;
typedef __attribute__((address_space(1))) const uint32_t gu32;
typedef __attribute__((address_space(3))) uint32_t lu32;

#if __has_builtin(__builtin_amdgcn_exp2f)
#define EXP2F __builtin_amdgcn_exp2f
#else
#define EXP2F exp2f
#endif

__device__ __forceinline__ float sigmoidf_(float x) { return 1.f / (1.f + __expf(-x)); }

__device__ __forceinline__ unsigned short f2bf(float f) {
    union { float f; uint32_t u; } v; v.f = f;
    uint32_t r = v.u + 0x7FFF + ((v.u >> 16) & 1);
    return (unsigned short)(r >> 16);
}
__device__ __forceinline__ float bf2f(unsigned short h) {
    union { uint32_t u; float f; } v; v.u = ((uint32_t)h) << 16;
    return v.f;
}

__device__ __forceinline__ void gld16(const void* g, void* l) {
    __builtin_amdgcn_global_load_lds((gu32*)g, (lu32*)l, 16, 0, 0);
}

template <int N> __device__ __forceinline__ void waitv() {
    if constexpr (N == 0)       asm volatile("s_waitcnt vmcnt(0)" ::: "memory");
    else if constexpr (N == 3)  asm volatile("s_waitcnt vmcnt(3)" ::: "memory");
    else if constexpr (N == 4)  asm volatile("s_waitcnt vmcnt(4)" ::: "memory");
    else if constexpr (N == 5)  asm volatile("s_waitcnt vmcnt(5)" ::: "memory");
    else if constexpr (N == 6)  asm volatile("s_waitcnt vmcnt(6)" ::: "memory");
    else if constexpr (N == 8)  asm volatile("s_waitcnt vmcnt(8)" ::: "memory");
    else if constexpr (N == 10) asm volatile("s_waitcnt vmcnt(10)" ::: "memory");
    else if constexpr (N == 16) asm volatile("s_waitcnt vmcnt(16)" ::: "memory");
}

// ---------------- prep: ALL weight transposes in one launch (8 -> 1 dispatch) ----
__global__ __launch_bounds__(256) void wtrans_all(
    const float* __restrict__ W_in, const float* __restrict__ W_inpr,
    const float* __restrict__ W_out, const float* __restrict__ W_xproj,
    const float* __restrict__ W_outp,
    unsigned short* __restrict__ WinT, unsigned short* __restrict__ WipT,
    unsigned short* __restrict__ WoutT, unsigned short* __restrict__ WxpT,
    unsigned short* __restrict__ WopT)
{
    const int bid = blockIdx.x, tid = threadIdx.x;
    if (bid < 1088) {                              // W_in: K=1088, N=256
        int idx = bid * 256 + tid;
        int n = idx / 1088, k = idx % 1088;
        WinT[idx] = f2bf(W_in[(size_t)k * 256 + n]);
    } else if (bid < 3136) {                       // W_inpr: K=256, N=1024 (x2)
        int l = (bid - 1088) >> 10;
        int idx = ((bid - 1088) & 1023) * 256 + tid;
        int n = idx >> 8, k = idx & 255;
        WipT[(size_t)l * 262144 + idx] = f2bf(W_inpr[(size_t)l * 262144 + (size_t)k * 1024 + n]);
    } else if (bid < 4160) {                       // W_out: K=512, N=256 (x2)
        int l = (bid - 3136) >> 9;
        int idx = ((bid - 3136) & 511) * 256 + tid;
        int n = idx >> 9, k = idx & 511;
        WoutT[(size_t)l * 131072 + idx] = f2bf(W_out[(size_t)l * 131072 + (size_t)k * 256 + n]);
    } else if (bid < 4672) {                       // W_xproj: K=512, Nreal=48, Npad=128 (x2)
        int l = (bid - 4160) >> 8;
        int idx = ((bid - 4160) & 255) * 256 + tid;
        int n = idx >> 9, k = idx & 511;
        WxpT[(size_t)l * 65536 + idx] =
            (n < 48) ? f2bf(W_xproj[(size_t)l * (512 * 48) + (size_t)k * 48 + n]) : (unsigned short)0;
    } else {                                       // W_outp: K=256, Nreal=64, Npad=128
        int idx = (bid - 4672) * 256 + tid;
        int n = idx >> 8, k = idx & 255;
        WopT[idx] = (n < 64) ? f2bf(W_outp[(size_t)k * 64 + n]) : (unsigned short)0;
    }
}

// ---------------- bf16 MFMA GEMM, double-buffered LDS + COUNTED vmcnt ----------------
// C(M x Nout) = A(MxK) @ Bt(NxK)^T.  Tile TM x TN; BK in {32, 64}.
// R1-R9 models: slot model (rounds/CU / resident x ~2.2us) AND staged-bytes
// model (bytes / ~7.1 TB/s) both validated; TN=256@TM=64 (acc 64 VGPR, LDS
// <= 48KB, res 2) is the config where they diverge -> this round's A/B.
// Levers that fail: depth>2 (R2), split-K (R3), reg-B (R5), 1-resident fat
// tiles (R6), TN=256@TM=128 VGPR cliff (R7).
// Row-bytes >= 128 -> XOR swizzle (col ^= (row&7)<<4) on pre-swizzled source
// + frag read (rule 21).
// LN64OUT: fuse final LayerNorm(64) into epilogue (wc=0 waves own full row).
// LN256OUT (needs TN=256=Nout): fuse LayerNorm(256); waves w,w^1 share rows
// with complementary 128-col halves -> fr-group shfl_xor partials + 1KB LDS
// (reused Alds) cross-wave-pair exchange. Writes x (f32 pre-LN, residual)
// AND xn (bf16 LN'd).
template <int TM, int TN, int BK, bool A_F32, bool HAS_BIAS, bool HAS_RES,
          bool OUT_BF16, bool LN64OUT, bool LN256OUT>
__global__ __launch_bounds__(256) void gemm_bf16(
    const void* __restrict__ Aptr, const unsigned short* __restrict__ Bt,
    const float* __restrict__ bias, const float* __restrict__ res,
    void* __restrict__ Cout, int M, int N, int K, int Nout,
    const float* __restrict__ lng, const float* __restrict__ lnb,
    unsigned short* __restrict__ xnout)
{
    constexpr int MR = TM / 32;                 // 16-row m-frags per wave (wave owns TM/2 rows)
    constexpr int NR = TN / 32;                 // 16-col n-frags per wave (wave owns TN/2 cols)
    constexpr int EWA = A_F32 ? 4 : 2;
    constexpr int RBA = BK * EWA;               // A tile row bytes
    constexpr int RBB = BK * 2;                 // B tile row bytes
    constexpr int ABYTES = TM * RBA;
    constexpr int BBYTES = TN * RBB;
    constexpr int OPSA = ABYTES / 4096;         // gld16 instrs per thread (A)
    constexpr int OPSB = BBYTES / 4096;
    constexpr int VOPS = OPSA + OPSB;
    constexpr bool SWZA = (RBA >= 128);
    constexpr bool SWZB = (RBB >= 128);
    constexpr int KK = BK / 32;                 // MFMA k-substeps per round
    __shared__ __align__(16) char Alds[2][ABYTES];
    __shared__ __align__(16) char Blds[2][BBYTES];
    const int tid = threadIdx.x;
    const int w = tid >> 6, lane = tid & 63;

    // bijective XCD-chunked swizzle (nwg % 8 == 0 for all our shapes)
    const int nwg = gridDim.x;
    const int q = nwg >> 3;
    const int wg = (blockIdx.x & 7) * q + (blockIdx.x >> 3);
    const int nx = N / TN;
    const int bm = (wg / nx) * TM, bn = (wg % nx) * TN;

    const int wr = (w >> 1) * (TM / 2), wc = (w & 1) * (TN / 2);
    const int fr = lane & 15, fq = lane >> 4;
    const size_t KbB = (size_t)K * 2;
    const size_t KbA = (size_t)K * EWA;

    const char* Ab = (const char*)Aptr;
    const char* Bb = (const char*)Bt;
    const int lds0 = w * 1024;                  // wave-uniform dest offset, bytes

    f32x4 acc[MR][NR];
#pragma unroll
    for (int m = 0; m < MR; m++)
#pragma unroll
        for (int n = 0; n < NR; n++) acc[m][n] = (f32x4){0.f, 0.f, 0.f, 0.f};

    auto stageA = [&](int buf, int k0) {
        char* lA = Alds[buf];
#pragma unroll
        for (int i = 0; i < OPSA; i++) {
            const int o = i * 4096 + tid * 16;
            const int row = o / RBA;
            int col = o % RBA;
            if constexpr (SWZA) col ^= (row & 7) << 4;
            gld16(Ab + (size_t)(bm + row) * KbA + (size_t)k0 * EWA + col,
                  lA + i * 4096 + lds0);
        }
    };
    auto stageB = [&](int buf, int k0) {
        char* lB = Blds[buf];
#pragma unroll
        for (int i = 0; i < OPSB; i++) {
            const int o = i * 4096 + tid * 16;
            const int row = o / RBB;
            int col = o % RBB;
            if constexpr (SWZB) col ^= (row & 7) << 4;
            gld16(Bb + (size_t)(bn + row) * KbB + (size_t)k0 * 2 + col,
                  lB + i * 4096 + lds0);
        }
    };
    auto compute = [&](int buf) {
        const char* lA = Alds[buf];
        const char* lB = Blds[buf];
#pragma unroll
        for (int kk = 0; kk < KK; kk++) {        // kk-outer keeps frag regs small
            bf16x8 af[MR], bg[NR];
#pragma unroll
            for (int m = 0; m < MR; m++) {
                const int row = wr + m * 16 + fr;
                const int sw = SWZA ? ((row & 7) << 4) : 0;
                if constexpr (A_F32) {
                    const int b0 = row * RBA + kk * 128 + fq * 32;
                    float4 x0 = *(const float4*)(lA + (b0 ^ sw));
                    float4 x1 = *(const float4*)(lA + ((b0 + 16) ^ sw));
                    bf16x8 a;
                    a[0]=(__bf16)x0.x; a[1]=(__bf16)x0.y; a[2]=(__bf16)x0.z; a[3]=(__bf16)x0.w;
                    a[4]=(__bf16)x1.x; a[5]=(__bf16)x1.y; a[6]=(__bf16)x1.z; a[7]=(__bf16)x1.w;
                    af[m] = a;
                } else {
                    const int c = kk * 64 + fq * 16;
                    af[m] = *(const bf16x8*)(lA + row * RBA + (c ^ sw));
                }
            }
#pragma unroll
            for (int n = 0; n < NR; n++) {
                const int row = wc + n * 16 + fr;
                const int sw = SWZB ? ((row & 7) << 4) : 0;
                const int c = kk * 64 + fq * 16;
                bg[n] = *(const bf16x8*)(lB + row * RBB + (c ^ sw));
            }
#pragma unroll
            for (int m = 0; m < MR; m++)
#pragma unroll
                for (int n = 0; n < NR; n++)
                    acc[m][n] = __builtin_amdgcn_mfma_f32_16x16x32_bf16(af[m], bg[n], acc[m][n], 0, 0, 0);
        }
    };

    const int NT = K / BK;

    // ---- prologue: stage tile 0 into buf 0, full drain once ----
    stageA(0, 0); stageB(0, 0);
    asm volatile("s_waitcnt vmcnt(0) lgkmcnt(0)" ::: "memory");
    __builtin_amdgcn_s_barrier();
    __builtin_amdgcn_sched_barrier(0);

    for (int kt = 0; kt < NT; ++kt) {
        const int cur = kt & 1;
        const bool has_next = (kt + 1 < NT);
        if (has_next) {
            const int k0 = (kt + 1) * BK;
            stageA(cur ^ 1, k0); stageB(cur ^ 1, k0);
            waitv<VOPS>();          // current tile only; next stays in flight
        } else {
            waitv<0>();
        }
        __builtin_amdgcn_s_barrier();
        __builtin_amdgcn_sched_barrier(0);

        compute(cur);

        asm volatile("s_waitcnt lgkmcnt(0)" ::: "memory");
        __builtin_amdgcn_s_barrier();
        __builtin_amdgcn_sched_barrier(0);
    }

    if constexpr (LN256OUT) {
        // TN == 256 == Nout, nx == 1 (bn == 0). Waves w and w^1 share rows.
        float* xout = (float*)Cout;
        float s_[MR][4], sq_[MR][4];
#pragma unroll
        for (int m = 0; m < MR; m++)
#pragma unroll
            for (int r = 0; r < 4; r++) { s_[m][r] = 0.f; sq_[m][r] = 0.f; }
#pragma unroll
        for (int m = 0; m < MR; m++) {
#pragma unroll
            for (int n = 0; n < NR; n++) {
                const int col = wc + n * 16 + fr;
#pragma unroll
                for (int r = 0; r < 4; r++) {
                    const int row = bm + wr + m * 16 + fq * 4 + r;
                    float v = acc[m][n][r];
                    if (HAS_BIAS) v += bias[col];
                    if (HAS_RES)  v += res[(size_t)row * 256 + col];
                    acc[m][n][r] = v;
                    xout[(size_t)row * 256 + col] = v;
                    s_[m][r] += v; sq_[m][r] += v * v;
                }
            }
        }
#pragma unroll
        for (int m = 0; m < MR; m++)
#pragma unroll
            for (int r = 0; r < 4; r++)
#pragma unroll
                for (int off = 8; off; off >>= 1) {
                    s_[m][r] += __shfl_xor(s_[m][r], off);
                    sq_[m][r] += __shfl_xor(sq_[m][r], off);
                }
        // cross-wave-pair exchange (reuse Alds; last loop iter ended with a
        // full barrier so all LDS reads of Alds are complete)
        float2* red = (float2*)&Alds[0][0];
        if (fr == 0) {
#pragma unroll
            for (int m = 0; m < MR; m++)
#pragma unroll
                for (int r = 0; r < 4; r++)
                    red[w * 32 + m * 16 + fq * 4 + r] = make_float2(s_[m][r], sq_[m][r]);
        }
        __syncthreads();
#pragma unroll
        for (int m = 0; m < MR; m++) {
#pragma unroll
            for (int r = 0; r < 4; r++) {
                float2 o = red[(w ^ 1) * 32 + m * 16 + fq * 4 + r];
                float s = s_[m][r] + o.x, sq = sq_[m][r] + o.y;
                float mean = s * (1.f / 256.f);
                float var = sq * (1.f / 256.f) - mean * mean;
                float rs = rsqrtf(var + 1e-5f);
                const int row = bm + wr + m * 16 + fq * 4 + r;
#pragma unroll
                for (int n = 0; n < NR; n++) {
                    const int col = wc + n * 16 + fr;
                    xnout[(size_t)row * 256 + col] =
                        f2bf((acc[m][n][r] - mean) * rs * lng[col] + lnb[col]);
                }
            }
        }
    } else if constexpr (LN64OUT) {
        // wc=0 waves hold cols 0..63 of their rows: col = n*16+fr (NR=4).
        if (wc == 0) {
#pragma unroll
            for (int m = 0; m < MR; m++) {
#pragma unroll
                for (int r = 0; r < 4; r++) {
                    float v[NR]; float s = 0.f, sq = 0.f;
#pragma unroll
                    for (int n = 0; n < NR; n++) {
                        v[n] = acc[m][n][r] + bias[n * 16 + fr];
                        s += v[n]; sq += v[n] * v[n];
                    }
#pragma unroll
                    for (int off = 8; off; off >>= 1) { s += __shfl_xor(s, off); sq += __shfl_xor(sq, off); }
                    float mean = s * (1.f / 64.f);
                    float var = sq * (1.f / 64.f) - mean * mean;
                    float rs = rsqrtf(var + 1e-5f);
                    int row = bm + wr + m * 16 + fq * 4 + r;
#pragma unroll
                    for (int n = 0; n < NR; n++) {
                        int col = n * 16 + fr;
                        ((float*)Cout)[(size_t)row * 64 + col] = (v[n] - mean) * rs * lng[col] + lnb[col];
                    }
                }
            }
        }
    } else {
#pragma unroll
        for (int m = 0; m < MR; m++) {
#pragma unroll
            for (int n = 0; n < NR; n++) {
                int col = bn + wc + n * 16 + fr;
                if (col < Nout) {
#pragma unroll
                    for (int r = 0; r < 4; r++) {
                        int row = bm + wr + m * 16 + fq * 4 + r;
                        float v = acc[m][n][r];
                        if (HAS_BIAS) v += bias[col];
                        if (HAS_RES)  v += res[(size_t)row * Nout + col];
                        if (OUT_BF16) ((unsigned short*)Cout)[(size_t)row * Nout + col] = f2bf(v);
                        else          ((float*)Cout)[(size_t)row * Nout + col] = v;
                    }
                }
            }
        }
    }
}

// ---------------- Depthwise causal conv (K=4) + bias + silu, 8 d per thread ----------------
__global__ __launch_bounds__(256) void conv_silu8(
    const unsigned short* __restrict__ xz, const float* __restrict__ w,
    const float* __restrict__ cb, unsigned short* __restrict__ xc)
{
    int idx = blockIdx.x * 256 + threadIdx.x;     // NROWS*64 threads
    int d8 = (idx & 63) << 3;                     // lane -> d-group (coalesced)
    int l  = (idx >> 6) & 2047;
    int b  = idx >> 17;
    const unsigned short* base = xz + ((size_t)b * L_SEQ + l) * 1024 + d8;
    u16x8 t0 = {0,0,0,0,0,0,0,0}, t1 = t0, t2 = t0;
    u16x8 t3 = *(const u16x8*)base;
    if (l >= 1) t2 = *(const u16x8*)(base - 1024);
    if (l >= 2) t1 = *(const u16x8*)(base - 2048);
    if (l >= 3) t0 = *(const u16x8*)(base - 3072);
    u16x8 o;
#pragma unroll
    for (int j = 0; j < 8; j++) {
        float4 wv = *(const float4*)&w[(d8 + j) * 4];
        float acc = cb[d8 + j];
        acc = fmaf(bf2f(t0[j]), wv.x, acc);
        acc = fmaf(bf2f(t1[j]), wv.y, acc);
        acc = fmaf(bf2f(t2[j]), wv.z, acc);
        acc = fmaf(bf2f(t3[j]), wv.w, acc);
        o[j] = f2bf(acc * sigmoidf_(acc));
    }
    *(u16x8*)&xc[((size_t)b * L_SEQ + l) * 512 + d8] = o;
}

// ---------------- Chunked selective scan (dt fused in-register; P stored as
// scalar Tsum per (b,c,d) -- P[n]=exp2(Tsum*a2[n]) is recomputed in pass2) ----------------
__global__ __launch_bounds__(256) void scan_pass1(
    const unsigned short* __restrict__ xc, const float* __restrict__ xdbl,
    const float* __restrict__ Wdt, const float* __restrict__ bdt,
    const float* __restrict__ Alog,
    float* __restrict__ Tbuf, float* __restrict__ Sbuf)
{
    __shared__ float xs[T_CH][32];   // [t][0:16]=dt-proj inputs, [16:32]=B
    int idx = blockIdx.x * 256 + threadIdx.x;
    int d = idx & 511;
    int c = (idx >> 9) & (C_CH - 1);
    int b = idx >> 14;
    size_t r0 = (size_t)b * L_SEQ + (size_t)c * T_CH;
#pragma unroll
    for (int ii = 0; ii < 2; ii++) {
        int i = threadIdx.x + ii * 256, row = i >> 3, qq = i & 7;
        *(float4*)&xs[row][qq * 4] = *(const float4*)&xdbl[(r0 + row) * 48 + qq * 4];
    }
    __syncthreads();

    float wdt[16];
#pragma unroll
    for (int j = 0; j < 16; j++) wdt[j] = Wdt[j * 512 + d];
    const float bd = bdt[d];

    float a[16], a2[16], S[16];
#pragma unroll
    for (int n = 0; n < 16; n++) a[n] = -__expf(Alog[d * 16 + n]);
#pragma unroll
    for (int n = 0; n < 16; n++) a2[n] = a[n] * LOG2E;
#pragma unroll
    for (int n = 0; n < 16; n++) S[n] = 0.f;
    bool pow_ok = true;
#pragma unroll
    for (int n = 1; n < 16; n++)
        pow_ok = pow_ok && (fabsf(a[n] - (n + 1) * a[0]) <= 1e-3f * (n + 1) * fabsf(a[0]));
    const float a0l2 = a[0] * LOG2E;
    float Tsum = 0.f;

    if (pow_ok) {
        for (int t = 0; t < T_CH; t++) {
            float dtr = bd;
#pragma unroll
            for (int j = 0; j < 16; j++) dtr = fmaf(xs[t][j], wdt[j], dtr);
            float dtv = (dtr > 20.f) ? dtr : __logf(1.f + __expf(dtr));
            float u = bf2f(xc[(r0 + t) * 512 + d]);
            float dtu = dtv * u;
            Tsum += dtv;
            float e1 = EXP2F(dtv * a0l2), e2 = e1 * e1;
            S[0] = fmaf(e1, S[0], dtu * xs[t][16]);
            S[1] = fmaf(e2, S[1], dtu * xs[t][17]);
            float pm2 = e1, pm1 = e2;
#pragma unroll
            for (int n = 2; n < 16; n++) {
                float cur = pm2 * e2;
                S[n] = fmaf(cur, S[n], dtu * xs[t][16 + n]);
                pm2 = pm1; pm1 = cur;
            }
        }
    } else {
        for (int t = 0; t < T_CH; t++) {
            float dtr = bd;
#pragma unroll
            for (int j = 0; j < 16; j++) dtr = fmaf(xs[t][j], wdt[j], dtr);
            float dtv = (dtr > 20.f) ? dtr : __logf(1.f + __expf(dtr));
            float u = bf2f(xc[(r0 + t) * 512 + d]);
            float dtu = dtv * u;
            Tsum += dtv;
#pragma unroll
            for (int n = 0; n < 16; n++) {
                float dA = EXP2F(dtv * a2[n]);
                S[n] = fmaf(dA, S[n], dtu * xs[t][16 + n]);
            }
        }
    }
    Tbuf[idx] = Tsum;
    size_t o = (size_t)idx * 16;
#pragma unroll
    for (int qq = 0; qq < 4; qq++)
        *(float4*)&Sbuf[o + qq * 4] = make_float4(S[qq*4], S[qq*4+1], S[qq*4+2], S[qq*4+3]);
}

__global__ __launch_bounds__(256) void scan_pass2(
    const float* __restrict__ Tbuf, const float* __restrict__ Alog,
    float* __restrict__ Sbuf)
{
    int g = blockIdx.x * 256 + threadIdx.x;
    int nd = g & 8191;
    int b = g >> 13;
    int d = nd >> 4, n = nd & 15;
    const float a2 = -__expf(Alog[d * 16 + n]) * LOG2E;
    float H = 0.f;
    for (int c = 0; c < C_CH; c++) {
        size_t base = (size_t)(b * C_CH + c);
        float T = Tbuf[base * 512 + d];
        float P = EXP2F(T * a2);
        size_t idx = base * 8192 + nd;
        float S = Sbuf[idx];
        float Hn = fmaf(P, H, S);
        Sbuf[idx] = H;
        H = Hn;
    }
}

__global__ __launch_bounds__(256) void scan_pass3(
    const unsigned short* __restrict__ xcin, const unsigned short* __restrict__ xz,
    const float* __restrict__ xdbl, const float* __restrict__ Wdt,
    const float* __restrict__ bdt, const float* __restrict__ Alog,
    const float* __restrict__ Dsk, const float* __restrict__ Sbuf,
    unsigned short* __restrict__ y)
{
    __shared__ float xs[T_CH][48];   // [t][0:16]=dt-in, [16:32]=B, [32:48]=C
    int idx = blockIdx.x * 256 + threadIdx.x;
    int d = idx & 511;
    int c = (idx >> 9) & (C_CH - 1);
    int b = idx >> 14;
    size_t r0 = (size_t)b * L_SEQ + (size_t)c * T_CH;
#pragma unroll
    for (int ii = 0; ii < 3; ii++) {
        int i = threadIdx.x + ii * 256, row = i / 12, qq = i % 12;
        *(float4*)&xs[row][qq * 4] = *(const float4*)&xdbl[(r0 + row) * 48 + qq * 4];
    }
    __syncthreads();

    float wdt[16];
#pragma unroll
    for (int j = 0; j < 16; j++) wdt[j] = Wdt[j * 512 + d];
    const float bd = bdt[d];

    float a[16], a2[16], h[16];
#pragma unroll
    for (int n = 0; n < 16; n++) a[n] = -__expf(Alog[d * 16 + n]);
#pragma unroll
    for (int n = 0; n < 16; n++) a2[n] = a[n] * LOG2E;
    {
        size_t o = (size_t)idx * 16;
#pragma unroll
        for (int qq = 0; qq < 4; qq++) {
            float4 v = *(const float4*)&Sbuf[o + qq * 4];
            h[qq*4] = v.x; h[qq*4+1] = v.y; h[qq*4+2] = v.z; h[qq*4+3] = v.w;
        }
    }
    bool pow_ok = true;
#pragma unroll
    for (int n = 1; n < 16; n++)
        pow_ok = pow_ok && (fabsf(a[n] - (n + 1) * a[0]) <= 1e-3f * (n + 1) * fabsf(a[0]));
    const float a0l2 = a[0] * LOG2E;
    const float Dv = Dsk[d];

    if (pow_ok) {
        for (int t = 0; t < T_CH; t++) {
            size_t ridx = (r0 + t) * 512 + d;
            float dtr = bd;
#pragma unroll
            for (int j = 0; j < 16; j++) dtr = fmaf(xs[t][j], wdt[j], dtr);
            float dtv = (dtr > 20.f) ? dtr : __logf(1.f + __expf(dtr));
            float u = bf2f(xcin[ridx]);
            float dtu = dtv * u;
            float e1 = EXP2F(dtv * a0l2), e2 = e1 * e1;
            float yv = 0.f;
            h[0] = fmaf(e1, h[0], dtu * xs[t][16]);  yv = fmaf(h[0], xs[t][32], yv);
            h[1] = fmaf(e2, h[1], dtu * xs[t][17]);  yv = fmaf(h[1], xs[t][33], yv);
            float pm2 = e1, pm1 = e2;
#pragma unroll
            for (int n = 2; n < 16; n++) {
                float cur = pm2 * e2;
                h[n] = fmaf(cur, h[n], dtu * xs[t][16 + n]);
                yv = fmaf(h[n], xs[t][32 + n], yv);
                pm2 = pm1; pm1 = cur;
            }
            yv = fmaf(u, Dv, yv);
            float z = bf2f(xz[(r0 + t) * 1024 + 512 + d]);
            y[ridx] = f2bf(yv * z * sigmoidf_(z));
        }
    } else {
        for (int t = 0; t < T_CH; t++) {
            size_t ridx = (r0 + t) * 512 + d;
            float dtr = bd;
#pragma unroll
            for (int j = 0; j < 16; j++) dtr = fmaf(xs[t][j], wdt[j], dtr);
            float dtv = (dtr > 20.f) ? dtr : __logf(1.f + __expf(dtr));
            float u = bf2f(xcin[ridx]);
            float dtu = dtv * u;
            float yv = 0.f;
#pragma unroll
            for (int n = 0; n < 16; n++) {
                float dA = EXP2F(dtv * a2[n]);
                h[n] = fmaf(dA, h[n], dtu * xs[t][16 + n]);
                yv = fmaf(h[n], xs[t][32 + n], yv);
            }
            yv = fmaf(u, Dv, yv);
            float z = bf2f(xz[(r0 + t) * 1024 + 512 + d]);
            y[ridx] = f2bf(yv * z * sigmoidf_(z));
        }
    }
}

extern "C" void kernel_launch(void* const* d_in, const int* in_sizes, int n_in,
                              void* d_out, int out_size, void* d_ws, size_t ws_size,
                              hipStream_t stream)
{
    const float* z_t     = (const float*)d_in[0];
    const float* W_in    = (const float*)d_in[1];
    const float* b_in    = (const float*)d_in[2];
    const float* ln_g    = (const float*)d_in[3];
    const float* ln_b    = (const float*)d_in[4];
    const float* W_inpr  = (const float*)d_in[5];
    const float* conv_w  = (const float*)d_in[6];
    const float* conv_b  = (const float*)d_in[7];
    const float* W_xproj = (const float*)d_in[8];
    const float* W_dt    = (const float*)d_in[9];
    const float* b_dt    = (const float*)d_in[10];
    const float* A_log   = (const float*)d_in[11];
    const float* D_skip  = (const float*)d_in[12];
    const float* W_out   = (const float*)d_in[13];
    const float* W_outp  = (const float*)d_in[14];
    const float* b_outp  = (const float*)d_in[15];
    const float* lno_g   = (const float*)d_in[16];
    const float* lno_b   = (const float*)d_in[17];
    float* out           = (float*)d_out;

    // Workspace (~119 MB + weights)
    char* p = (char*)d_ws;
    float*          x    = (float*)p;          p += (size_t)NROWS * DMODEL * 4;      // 32 MB
    unsigned short* xn   = (unsigned short*)p; p += (size_t)NROWS * DMODEL * 2;      // 16 MB
    unsigned short* xc   = (unsigned short*)p; p += (size_t)NROWS * DINNER * 2;      // 32 MB
    unsigned short* xz   = (unsigned short*)p; p += (size_t)NROWS * 1024 * 2;        // 64 MB
    float*          xdbl = (float*)p;          p += (size_t)NROWS * 48 * 4;          // 6.3 MB
    float*          Pregion = (float*)p;       p += (size_t)BATCH * C_CH * DINNER * 16 * 4; // 16.8
    float*          Sbuf = (float*)p;          p += (size_t)BATCH * C_CH * DINNER * 16 * 4; // 16.8
    unsigned short* WinT  = (unsigned short*)p; p += (size_t)256 * 1088 * 2;
    unsigned short* WipT  = (unsigned short*)p; p += (size_t)2 * 1024 * 256 * 2;
    unsigned short* WoutT = (unsigned short*)p; p += (size_t)2 * 256 * 512 * 2;
    unsigned short* WxpT  = (unsigned short*)p; p += (size_t)2 * 128 * 512 * 2;
    unsigned short* WopT  = (unsigned short*)p; p += (size_t)128 * 256 * 2;
    // alias (timeline-disjoint):
    float* Tbuf = Pregion;   // 1 MB: pass1 -> pass2, per layer

    // prep: all weight transposes in ONE launch
    wtrans_all<<<4800, 256, 0, stream>>>(W_in, W_inpr, W_out, W_xproj, W_outp,
                                         WinT, WipT, WoutT, WxpT, WopT);

    // x = z_t @ W_in + b_in, with layer-0 LN(256) fused in the epilogue
    // (TM=64/TN=256/BK=32: A read exactly once -> staged bytes 570->427MB)
    gemm_bf16<64, 256, 32, true, true, false, false, false, true><<<NROWS / 64, 256, 0, stream>>>(
        z_t, WinT, b_in, nullptr, x, NROWS, 256, 1088, 256, ln_g, ln_b, xn);

    for (int layer = 0; layer < 2; ++layer) {
        // inproj: R9 config (TM=128/TN=128/BK=64)
        gemm_bf16<128, 128, 64, false, false, false, true, false, false><<<(NROWS / 128) * (1024 / 128), 256, 0, stream>>>(
            xn, WipT + (size_t)layer * 1024 * 256, nullptr, nullptr, xz, NROWS, 1024, 256, 1024,
            nullptr, nullptr, nullptr);
        conv_silu8<<<NROWS * 64 / 256, 256, 0, stream>>>(
            xz, conv_w + layer * 512 * 4, conv_b + layer * 512, xc);
        gemm_bf16<64, 128, 64, false, false, false, false, false, false><<<(NROWS / 64) * (128 / 128), 256, 0, stream>>>(
            xc, WxpT + (size_t)layer * 128 * 512, nullptr, nullptr, xdbl, NROWS, 128, 512, 48,
            nullptr, nullptr, nullptr);

        const float* Al_l  = A_log + layer * 512 * 16;
        const float* Wdt_l = W_dt + layer * 16 * 512;
        const float* bdt_l = b_dt + layer * 512;
        scan_pass1<<<BATCH * C_CH * DINNER / 256, 256, 0, stream>>>(
            xc, xdbl, Wdt_l, bdt_l, Al_l, Tbuf, Sbuf);
        scan_pass2<<<BATCH * DINNER * 16 / 256, 256, 0, stream>>>(Tbuf, Al_l, Sbuf);
        scan_pass3<<<BATCH * C_CH * DINNER / 256, 256, 0, stream>>>(
            xc, xz, xdbl, Wdt_l, bdt_l, Al_l, D_skip + layer * 512, Sbuf, xc);

        if (layer == 0) {
            // x_new = x + y@W_out, with layer-1 LN(256) fused (writes x f32 + xn bf16)
            gemm_bf16<64, 256, 32, false, false, true, false, false, true><<<NROWS / 64, 256, 0, stream>>>(
                xc, WoutT, nullptr, x, x, NROWS, 256, 512, 256, ln_g + 256, ln_b + 256, xn);
        } else {
            // final residual add, emitted as bf16 directly (feeds out-proj GEMM)
            gemm_bf16<64, 128, 64, false, false, true, true, false, false><<<(NROWS / 64) * (256 / 128), 256, 0, stream>>>(
                xc, WoutT + (size_t)256 * 512, nullptr, x, xn, NROWS, 256, 512, 256,
                nullptr, nullptr, nullptr);
        }
    }

    // out-proj via MFMA (BK=64) with the final LayerNorm(64) fused
    gemm_bf16<64, 128, 64, false, true, false, false, true, false><<<(NROWS / 64) * (128 / 128), 256, 0, stream>>>(
        xn, WopT, b_outp, nullptr, out, NROWS, 128, 256, 64, lno_g, lno_b, nullptr);
}